// Round 12
// baseline (274.904 us; speedup 1.0000x reference)
//
#include <hip/hip_runtime.h>
#include <math.h>

// Problem constants
#define DIM   320
#define HD    40
#define NH    8
#define LQ    2048
#define BATCH 2
#define MROWS 4096
#define FFD   1280
#define FF2   2560

#define KSPLIT 4
#define KCHUNK (LQ/KSPLIT) // 512
#define KT     32
#define NQROWS (BATCH*NH*LQ)  // 32768

#define LSCALE (0.15811388300841897f * 1.4426950408889634f)

typedef unsigned short ushort_t;
using bf16x8 = __attribute__((ext_vector_type(8))) short;
using f32x4  = __attribute__((ext_vector_type(4))) float;

static __device__ inline ushort_t f2bf(float f) {
  union { float f; unsigned u; } x{f};
  unsigned r = x.u + 0x7FFFu + ((x.u >> 16) & 1u);
  return (ushort_t)(r >> 16);
}
static __device__ inline float bf2f(ushort_t h) {
  union { unsigned u; float f; } x; x.u = ((unsigned)h) << 16; return x.f;
}

#if __has_builtin(__builtin_amdgcn_exp2f)
#define EXP2F(x) __builtin_amdgcn_exp2f(x)
#else
#define EXP2F(x) exp2f(x)
#endif

// ---------------- LayerNorm: one wave per row of 320, bf16 out ---------------
__global__ __launch_bounds__(256) void ln_kernel(
    const float* __restrict__ X, const float* __restrict__ g,
    const float* __restrict__ bta, ushort_t* __restrict__ Y)
{
  int row  = blockIdx.x * 4 + (threadIdx.x >> 6);
  int lane = threadIdx.x & 63;
  const float* x = X + (size_t)row * DIM;
  float v[5];
  float s = 0.f;
#pragma unroll
  for (int i = 0; i < 5; ++i) { v[i] = x[lane + 64*i]; s += v[i]; }
#pragma unroll
  for (int off = 32; off >= 1; off >>= 1) s += __shfl_xor(s, off, 64);
  float mean = s * (1.0f/DIM);
  float sq = 0.f;
#pragma unroll
  for (int i = 0; i < 5; ++i) { float d = v[i] - mean; sq += d*d; }
#pragma unroll
  for (int off = 32; off >= 1; off >>= 1) sq += __shfl_xor(sq, off, 64);
  float rstd = rsqrtf(sq*(1.0f/DIM) + 1e-5f);
  ushort_t* y = Y + (size_t)row * DIM;
#pragma unroll
  for (int i = 0; i < 5; ++i) {
    int c = lane + 64*i;
    y[c] = f2bf((v[i]-mean)*rstd*g[c] + bta[c]);
  }
}

// ---------------- Weight convert/transpose to bf16, k-fastest ---------------
#define OFF_WQKVT 0
#define OFF_WO1T  (960*320)
#define OFF_WO2T  (OFF_WO1T + 320*320)
#define OFF_WFF1T (OFF_WO2T + 320*320)
#define OFF_WFF2T (OFF_WFF1T + 320*2560)
#define OFF_WVHB  (OFF_WFF2T + 1280*320)
#define WBF_TOTAL (OFF_WVHB + 320*320)

__global__ __launch_bounds__(256) void convw_kernel(
    const float* __restrict__ wq1, const float* __restrict__ wk1,
    const float* __restrict__ wv1, const float* __restrict__ wo1,
    const float* __restrict__ wo2, const float* __restrict__ wff1,
    const float* __restrict__ wff2, const float* __restrict__ wvh,
    ushort_t* __restrict__ dst)
{
  int e = blockIdx.y;
  const float* src; int K, N; size_t doff; int tr = 1; float scale = 1.f;
  switch (e) {
    case 0: src=wq1;  K=320;  N=320;  doff=OFF_WQKVT; scale=LSCALE; break;
    case 1: src=wk1;  K=320;  N=320;  doff=OFF_WQKVT + 320*320;  break;
    case 2: src=wv1;  K=320;  N=320;  doff=OFF_WQKVT + 2*320*320;break;
    case 3: src=wo1;  K=320;  N=320;  doff=OFF_WO1T;             break;
    case 4: src=wo2;  K=320;  N=320;  doff=OFF_WO2T;             break;
    case 5: src=wff1; K=320;  N=2560; doff=OFF_WFF1T;            break;
    case 6: src=wff2; K=1280; N=320;  doff=OFF_WFF2T;            break;
    default: src=wvh; K=320;  N=320;  doff=OFF_WVHB; tr=0;       break;
  }
  int ntN = N/32;
  int nt_total = (K/32)*ntN;
  int t = blockIdx.x;
  if (t >= nt_total) return;
  int kt = t / ntN, nt = t - kt*ntN;
  __shared__ float tile[32][33];
  int tx = threadIdx.x & 31, ty = threadIdx.x >> 5;
  ushort_t* d = dst + doff;
#pragma unroll
  for (int i = 0; i < 4; ++i) {
    int r = ty + 8*i;
    tile[r][tx] = src[(size_t)(kt*32+r)*N + nt*32+tx] * scale;
  }
  __syncthreads();
  if (tr) {
#pragma unroll
    for (int i = 0; i < 4; ++i) {
      int r = ty + 8*i;
      d[(size_t)(nt*32+r)*K + kt*32+tx] = f2bf(tile[tx][r]);
    }
  } else {
#pragma unroll
    for (int i = 0; i < 4; ++i) {
      int r = ty + 8*i;
      d[(size_t)(kt*32+r)*N + nt*32+tx] = f2bf(tile[r][tx]);
    }
  }
}

// ---- K/V repack: qkv [4096][960] -> Kp[16][2048][64] (d-pad 0) and
//      Vt[16][48][2048] (transposed, d-pad rows 0). Grid (32, 16).
__global__ __launch_bounds__(256) void vt_kernel(
    const ushort_t* __restrict__ qkv, ushort_t* __restrict__ Vt,
    ushort_t* __restrict__ Kp)
{
  int bh = blockIdx.y;
  int kt = blockIdx.x;
  int b = bh >> 3, h = bh & 7;
  int tid = threadIdx.x;
  __shared__ ushort_t tile[64*42];

  const ushort_t* ksrc = qkv + (size_t)(b*LQ + kt*64)*960 + DIM + h*HD;
  ushort_t* kdst = Kp + ((size_t)bh*2048 + (size_t)kt*64)*64;
#pragma unroll
  for (int i = 0; i < 2; ++i) {
    int f = i*256 + tid;
    if (f < 320) {
      int r = f/5, s = f - 5*r;
      *(uint4*)(kdst + r*64 + s*8) = *(const uint4*)(ksrc + (size_t)r*960 + s*8);
    }
  }
  if (tid < 192) {
    int r = tid/3, s = tid - 3*r;
    uint4 z = {0,0,0,0};
    *(uint4*)(kdst + r*64 + 40 + s*8) = z;
  }

  const ushort_t* vsrc = qkv + (size_t)(b*LQ + kt*64)*960 + 2*DIM + h*HD;
#pragma unroll
  for (int i = 0; i < 5; ++i) {
    int f = i*256 + tid;
    int r = f/20, c2 = f - r*20;
    *(unsigned*)(tile + r*42 + c2*2) = *(const unsigned*)(vsrc + (size_t)r*960 + c2*2);
  }
  __syncthreads();
  ushort_t* dstp = Vt + (size_t)bh*48*2048 + kt*64;
#pragma unroll
  for (int i = 0; i < 6; ++i) {
    int f = i*256 + tid;
    int dd = f >> 5, kk = f & 31;
    unsigned val = 0;
    if (dd < 40) {
      unsigned lo = tile[(kk*2)*42 + dd];
      unsigned hi = tile[(kk*2+1)*42 + dd];
      val = lo | (hi << 16);
    }
    *(unsigned*)(dstp + (size_t)dd*2048 + kk*2) = val;
  }
}

// ---------------- bf16 MFMA GEMM (TN), 64x64 tile, reg prefetch -------------
#define AS_STRIDE 40
__global__ __launch_bounds__(256) void mgemm(
    const ushort_t* __restrict__ A, int lda,
    const ushort_t* __restrict__ Bt, int ldb,
    const float* __restrict__ bias,
    const float* __restrict__ R,
    float* __restrict__ Cf, ushort_t* __restrict__ Cb, int ldc,
    int K)
{
  __shared__ ushort_t As[64*AS_STRIDE];
  __shared__ ushort_t Bs[64*AS_STRIDE];
  int tid = threadIdx.x;
  int w = tid >> 6, lane = tid & 63, quad = lane >> 4, n16 = lane & 15;
  int wm = w >> 1, wn = w & 1;
  int bm = blockIdx.y * 64, bn = blockIdx.x * 64;
  int sr = tid >> 2, sc = (tid & 3) << 3;
  const ushort_t* Ag = A  + (size_t)(bm + sr)*lda + sc;
  const ushort_t* Bg = Bt + (size_t)(bn + sr)*ldb + sc;

  f32x4 acc00 = {0.f,0.f,0.f,0.f}, acc01 = acc00, acc10 = acc00, acc11 = acc00;

  float4 av = *(const float4*)(Ag);
  float4 bv = *(const float4*)(Bg);
  for (int k0 = 0; k0 < K; k0 += 32) {
    __syncthreads();
    *(float4*)(As + sr*AS_STRIDE + sc) = av;
    *(float4*)(Bs + sr*AS_STRIDE + sc) = bv;
    __syncthreads();
    if (k0 + 32 < K) {
      av = *(const float4*)(Ag + k0 + 32);
      bv = *(const float4*)(Bg + k0 + 32);
    }
    bf16x8 fa0 = *(const bf16x8*)(As + (wm*32 +      n16)*AS_STRIDE + quad*8);
    bf16x8 fa1 = *(const bf16x8*)(As + (wm*32 + 16 + n16)*AS_STRIDE + quad*8);
    bf16x8 fb0 = *(const bf16x8*)(Bs + (wn*32 +      n16)*AS_STRIDE + quad*8);
    bf16x8 fb1 = *(const bf16x8*)(Bs + (wn*32 + 16 + n16)*AS_STRIDE + quad*8);
    acc00 = __builtin_amdgcn_mfma_f32_16x16x32_bf16(fa0, fb0, acc00, 0,0,0);
    acc01 = __builtin_amdgcn_mfma_f32_16x16x32_bf16(fa0, fb1, acc01, 0,0,0);
    acc10 = __builtin_amdgcn_mfma_f32_16x16x32_bf16(fa1, fb0, acc10, 0,0,0);
    acc11 = __builtin_amdgcn_mfma_f32_16x16x32_bf16(fa1, fb1, acc11, 0,0,0);
  }

  f32x4 accs[2][2] = {{acc00, acc01},{acc10, acc11}};
#pragma unroll
  for (int s = 0; s < 2; ++s)
#pragma unroll
    for (int t = 0; t < 2; ++t) {
      int c = bn + wn*32 + t*16 + n16;
      float bb = bias ? bias[c] : 0.f;
#pragma unroll
      for (int i = 0; i < 4; ++i) {
        int r = bm + wm*32 + s*16 + quad*4 + i;
        float v = accs[s][t][i] + bb;
        if (R)  v += R[(size_t)r*ldc + c];
        if (Cf) Cf[(size_t)r*ldc + c] = v;
        if (Cb) Cb[(size_t)r*ldc + c] = f2bf(v);
      }
    }
}

// ---------------- bf16 MFMA GEMM (TN), 128x64 tile — for N>=960 -------------
__global__ __launch_bounds__(256) void mgemm128(
    const ushort_t* __restrict__ A, int lda,
    const ushort_t* __restrict__ Bt, int ldb,
    ushort_t* __restrict__ Cb, int ldc, int K)
{
  __shared__ ushort_t As[128*AS_STRIDE];   // 10 KB
  __shared__ ushort_t Bs[64*AS_STRIDE];    // 5 KB
  int tid = threadIdx.x;
  int w = tid >> 6, lane = tid & 63, quad = lane >> 4, n16 = lane & 15;
  int wm = w >> 1, wn = w & 1;
  int bm = blockIdx.y * 128, bn = blockIdx.x * 64;
  int ar = tid >> 1, ac = (tid & 1) << 4;
  int br = tid >> 2, bc = (tid & 3) << 3;
  const ushort_t* Ag = A  + (size_t)(bm + ar)*lda + ac;
  const ushort_t* Bg = Bt + (size_t)(bn + br)*ldb + bc;

  f32x4 acc[4][2];
#pragma unroll
  for (int s = 0; s < 4; ++s)
#pragma unroll
    for (int t = 0; t < 2; ++t) acc[s][t] = f32x4{0.f,0.f,0.f,0.f};

  float4 av0 = *(const float4*)(Ag);
  float4 av1 = *(const float4*)(Ag + 8);
  float4 bv  = *(const float4*)(Bg);
  for (int k0 = 0; k0 < K; k0 += 32) {
    __syncthreads();
    *(float4*)(As + ar*AS_STRIDE + ac)     = av0;
    *(float4*)(As + ar*AS_STRIDE + ac + 8) = av1;
    *(float4*)(Bs + br*AS_STRIDE + bc)     = bv;
    __syncthreads();
    if (k0 + 32 < K) {
      av0 = *(const float4*)(Ag + k0 + 32);
      av1 = *(const float4*)(Ag + k0 + 40);
      bv  = *(const float4*)(Bg + k0 + 32);
    }
    bf16x8 fa[4], fb[2];
#pragma unroll
    for (int s = 0; s < 4; ++s)
      fa[s] = *(const bf16x8*)(As + (wm*64 + s*16 + n16)*AS_STRIDE + quad*8);
#pragma unroll
    for (int t = 0; t < 2; ++t)
      fb[t] = *(const bf16x8*)(Bs + (wn*32 + t*16 + n16)*AS_STRIDE + quad*8);
#pragma unroll
    for (int s = 0; s < 4; ++s)
#pragma unroll
      for (int t = 0; t < 2; ++t)
        acc[s][t] = __builtin_amdgcn_mfma_f32_16x16x32_bf16(fa[s], fb[t], acc[s][t], 0,0,0);
  }

#pragma unroll
  for (int s = 0; s < 4; ++s)
#pragma unroll
    for (int t = 0; t < 2; ++t) {
      int c = bn + wn*32 + t*16 + n16;
#pragma unroll
      for (int i = 0; i < 4; ++i) {
        int r = bm + wm*64 + s*16 + quad*4 + i;
        Cb[(size_t)r*ldc + c] = f2bf(acc[s][t][i]);
      }
    }
}

// -------- ff1 GEMM 128x64 + fused GEGLU: gegb = x * gelu(gate) --------------
__global__ __launch_bounds__(256) void ff1_geglu(
    const ushort_t* __restrict__ A, const ushort_t* __restrict__ Bt,
    const float* __restrict__ bias, ushort_t* __restrict__ Og)
{
  __shared__ ushort_t As[128*AS_STRIDE];
  __shared__ ushort_t Bxs[64*AS_STRIDE];
  __shared__ ushort_t Bgs[64*AS_STRIDE];
  int tid = threadIdx.x;
  int w = tid >> 6, lane = tid & 63, quad = lane >> 4, n16 = lane & 15;
  int wm = w >> 1, wn = w & 1;
  int bm = blockIdx.y * 128, bn = blockIdx.x * 64;
  int ar = tid >> 1, ac = (tid & 1) << 4;
  int br = tid >> 2, bc = (tid & 3) << 3;
  const ushort_t* Ag  = A  + (size_t)(bm + ar)*DIM + ac;
  const ushort_t* Bxg = Bt + (size_t)(bn + br)*DIM + bc;
  const ushort_t* Bgg = Bt + (size_t)(bn + FFD + br)*DIM + bc;

  f32x4 ax[4][2], ag[4][2];
#pragma unroll
  for (int s = 0; s < 4; ++s)
#pragma unroll
    for (int t = 0; t < 2; ++t) { ax[s][t] = f32x4{0.f,0.f,0.f,0.f}; ag[s][t] = ax[s][t]; }

  float4 av0 = *(const float4*)(Ag);
  float4 av1 = *(const float4*)(Ag + 8);
  float4 bxv = *(const float4*)(Bxg);
  float4 bgv = *(const float4*)(Bgg);
  for (int k0 = 0; k0 < DIM; k0 += 32) {
    __syncthreads();
    *(float4*)(As  + ar*AS_STRIDE + ac)     = av0;
    *(float4*)(As  + ar*AS_STRIDE + ac + 8) = av1;
    *(float4*)(Bxs + br*AS_STRIDE + bc)     = bxv;
    *(float4*)(Bgs + br*AS_STRIDE + bc)     = bgv;
    __syncthreads();
    if (k0 + 32 < DIM) {
      av0 = *(const float4*)(Ag  + k0 + 32);
      av1 = *(const float4*)(Ag  + k0 + 40);
      bxv = *(const float4*)(Bxg + k0 + 32);
      bgv = *(const float4*)(Bgg + k0 + 32);
    }
    bf16x8 fa[4], fx[2], fg[2];
#pragma unroll
    for (int s = 0; s < 4; ++s)
      fa[s] = *(const bf16x8*)(As + (wm*64 + s*16 + n16)*AS_STRIDE + quad*8);
#pragma unroll
    for (int t = 0; t < 2; ++t) {
      fx[t] = *(const bf16x8*)(Bxs + (wn*32 + t*16 + n16)*AS_STRIDE + quad*8);
      fg[t] = *(const bf16x8*)(Bgs + (wn*32 + t*16 + n16)*AS_STRIDE + quad*8);
    }
#pragma unroll
    for (int s = 0; s < 4; ++s)
#pragma unroll
      for (int t = 0; t < 2; ++t) {
        ax[s][t] = __builtin_amdgcn_mfma_f32_16x16x32_bf16(fa[s], fx[t], ax[s][t], 0,0,0);
        ag[s][t] = __builtin_amdgcn_mfma_f32_16x16x32_bf16(fa[s], fg[t], ag[s][t], 0,0,0);
      }
  }

  const float kk = 0.7071067811865476f;
#pragma unroll
  for (int s = 0; s < 4; ++s)
#pragma unroll
    for (int t = 0; t < 2; ++t) {
      int c = bn + wn*32 + t*16 + n16;
      float bx = bias[c], bg = bias[c + FFD];
#pragma unroll
      for (int i = 0; i < 4; ++i) {
        int r = bm + wm*64 + s*16 + quad*4 + i;
        float xx = ax[s][t][i] + bx;
        float gg = ag[s][t][i] + bg;
        Og[(size_t)r*FFD + c] = f2bf(xx * 0.5f * gg * (1.f + erff(gg * kk)));
      }
    }
}

// ---------------- MFMA flash attention: 1-wave blocks, fixed-max ------------
// The 4 waves of the old 256-block were fully independent (per-wave Ps, no
// __syncthreads) — as 64-thread blocks the scheduler can pack 4+ waves/SIMD
// (R11: (256,2) blocks pinned at 2 waves/SIMD resident, Occupancy 26%).
// Q pre-scaled via wq1. Kp[bh][2048][64], Vt[bh][48][2048]. XCD swizzle on
// low grid bits (R10: FETCH 31->6.7 MB). launch_bounds(64,4): VGPR cap 128,
// same as (256,2) -> no spill (R8 lesson). bf16 partials (R11 lesson).
#define PS_STRIDE 40

__global__ __launch_bounds__(64, 4) void attn_mfma(
    const ushort_t* __restrict__ qkv, const ushort_t* __restrict__ Kp,
    const ushort_t* __restrict__ Vt,
    float* __restrict__ Pl, ushort_t* __restrict__ Pacc)
{
  __shared__ ushort_t Psw[32*PS_STRIDE];
  int lane = threadIdx.x & 63;
  int quad = lane >> 4;
  int n16  = lane & 15;

  int blk  = blockIdx.x;
  int bh   = (blk & 7) | (((blk >> 3) & 1) << 3);
  int rest = blk >> 4;            // 0..255
  int w    = rest & 3;
  int qt   = (rest >> 2) & 15;
  int ks   = rest >> 6;           // 0..3
  int b = bh >> 3, h = bh & 7;

  const ushort_t* qrowa = qkv + (size_t)(b*LQ + qt*128 + w*32 + n16)*960 + h*HD;
  const ushort_t* qrowb = qrowa + 16*960;
  bf16x8 qf0a = *(const bf16x8*)(qrowa + quad*8);
  bf16x8 qf1a = *(const bf16x8*)(qrowa + 32);  // quads>0: garbage x Kp-pad(0) = 0
  bf16x8 qf0b = *(const bf16x8*)(qrowb + quad*8);
  bf16x8 qf1b = *(const bf16x8*)(qrowb + 32);

  const ushort_t* Kh = Kp + (size_t)bh*2048*64;
  const ushort_t* Vh = Vt + (size_t)bh*48*2048;
  int k0 = ks*KCHUNK;
  int koff0 = n16*64 + quad*8;
  int koff1 = (16+n16)*64 + quad*8;
  int voff = quad*8;

  f32x4 o0a = {0.f,0.f,0.f,0.f}, o1a = o0a, o2a = o0a;
  f32x4 o0b = o0a, o1b = o0a, o2b = o0a;
  f32x4 la0a = o0a, la1a = o0a, la0b = o0a, la1b = o0a;

#define LOAD_TILE(T0, K00,K01,K10,K11,V0,V1,V2) { \
  const ushort_t* Kt_ = Kh + (size_t)(k0 + (T0))*64; \
  const ushort_t* Vt_ = Vh + k0 + (T0); \
  K00 = *(const bf16x8*)(Kt_ + koff0); \
  K01 = *(const bf16x8*)(Kt_ + koff0 + 32); \
  K10 = *(const bf16x8*)(Kt_ + koff1); \
  K11 = *(const bf16x8*)(Kt_ + koff1 + 32); \
  V0 = *(const bf16x8*)(Vt_ + (size_t)(n16)*2048 + voff); \
  V1 = *(const bf16x8*)(Vt_ + (size_t)(16+n16)*2048 + voff); \
  V2 = *(const bf16x8*)(Vt_ + (size_t)(32+n16)*2048 + voff); }

#define COMPUTE(K00,K01,K10,K11,V0,V1,V2) { \
  f32x4 s0a = {-8.f,-8.f,-8.f,-8.f}; f32x4 s1a = s0a, s0b = s0a, s1b = s0a; \
  s0a = __builtin_amdgcn_mfma_f32_16x16x32_bf16(qf0a, K00, s0a, 0,0,0); \
  s1a = __builtin_amdgcn_mfma_f32_16x16x32_bf16(qf0a, K10, s1a, 0,0,0); \
  s0b = __builtin_amdgcn_mfma_f32_16x16x32_bf16(qf0b, K00, s0b, 0,0,0); \
  s1b = __builtin_amdgcn_mfma_f32_16x16x32_bf16(qf0b, K10, s1b, 0,0,0); \
  s0a = __builtin_amdgcn_mfma_f32_16x16x32_bf16(qf1a, K01, s0a, 0,0,0); \
  s1a = __builtin_amdgcn_mfma_f32_16x16x32_bf16(qf1a, K11, s1a, 0,0,0); \
  s0b = __builtin_amdgcn_mfma_f32_16x16x32_bf16(qf1b, K01, s0b, 0,0,0); \
  s1b = __builtin_amdgcn_mfma_f32_16x16x32_bf16(qf1b, K11, s1b, 0,0,0); \
  f32x4 p0a, p1a, p0b, p1b; \
  _Pragma("unroll") \
  for (int r = 0; r < 4; ++r) { \
    p0a[r] = EXP2F(s0a[r]); p1a[r] = EXP2F(s1a[r]); \
    p0b[r] = EXP2F(s0b[r]); p1b[r] = EXP2F(s1b[r]); \
  } \
  la0a += p0a; la1a += p1a; la0b += p0b; la1b += p1b; \
  _Pragma("unroll") \
  for (int r = 0; r < 4; ++r) { \
    int row = quad*4 + r; \
    Psw[row*PS_STRIDE + n16]           = (ushort_t)(__float_as_uint(p0a[r]) >> 16); \
    Psw[row*PS_STRIDE + 16 + n16]      = (ushort_t)(__float_as_uint(p1a[r]) >> 16); \
    Psw[(16+row)*PS_STRIDE + n16]      = (ushort_t)(__float_as_uint(p0b[r]) >> 16); \
    Psw[(16+row)*PS_STRIDE + 16 + n16] = (ushort_t)(__float_as_uint(p1b[r]) >> 16); \
  } \
  bf16x8 paa = *(const bf16x8*)(Psw + n16*PS_STRIDE + quad*8); \
  bf16x8 pab = *(const bf16x8*)(Psw + (16+n16)*PS_STRIDE + quad*8); \
  o0a = __builtin_amdgcn_mfma_f32_16x16x32_bf16(paa, V0, o0a, 0,0,0); \
  o0b = __builtin_amdgcn_mfma_f32_16x16x32_bf16(pab, V0, o0b, 0,0,0); \
  o1a = __builtin_amdgcn_mfma_f32_16x16x32_bf16(paa, V1, o1a, 0,0,0); \
  o1b = __builtin_amdgcn_mfma_f32_16x16x32_bf16(pab, V1, o1b, 0,0,0); \
  o2a = __builtin_amdgcn_mfma_f32_16x16x32_bf16(paa, V2, o2a, 0,0,0); \
  o2b = __builtin_amdgcn_mfma_f32_16x16x32_bf16(pab, V2, o2b, 0,0,0); }

  bf16x8 ka0,ka1,ka2,ka3,va0,va1,va2;
  bf16x8 kb0,kb1,kb2,kb3,vb0,vb1,vb2;
  LOAD_TILE(0, ka0,ka1,ka2,ka3,va0,va1,va2);
  for (int t0 = 0; t0 < KCHUNK; t0 += 2*KT) {
    LOAD_TILE(t0 + KT, kb0,kb1,kb2,kb3,vb0,vb1,vb2);
    COMPUTE(ka0,ka1,ka2,ka3,va0,va1,va2);
    if (t0 + 2*KT < KCHUNK) {
      LOAD_TILE(t0 + 2*KT, ka0,ka1,ka2,ka3,va0,va1,va2);
    }
    COMPUTE(kb0,kb1,kb2,kb3,vb0,vb1,vb2);
  }
#undef LOAD_TILE
#undef COMPUTE

  float lra[4], lrb[4];
#pragma unroll
  for (int r = 0; r < 4; ++r) { lra[r] = la0a[r] + la1a[r]; lrb[r] = la0b[r] + la1b[r]; }
#pragma unroll
  for (int off = 1; off < 16; off <<= 1)
#pragma unroll
    for (int r = 0; r < 4; ++r) {
      lra[r] += __shfl_xor(lra[r], off, 64);
      lrb[r] += __shfl_xor(lrb[r], off, 64);
    }

  int gqa = bh*LQ + qt*128 + w*32 + quad*4;
  size_t base = (size_t)ks*NQROWS;
#pragma unroll
  for (int r = 0; r < 4; ++r) {
    size_t gq = base + gqa + r;
    ushort_t* pw = Pacc + gq*40;
    pw[n16]      = f2bf(o0a[r]);
    pw[16 + n16] = f2bf(o1a[r]);
    if (n16 < 8) pw[32 + n16] = f2bf(o2a[r]);
    if (n16 == 0) Pl[gq] = lra[r];
    size_t gq2 = gq + 16;
    ushort_t* pw2 = Pacc + gq2*40;
    pw2[n16]      = f2bf(o0b[r]);
    pw2[16 + n16] = f2bf(o1b[r]);
    if (n16 < 8) pw2[32 + n16] = f2bf(o2b[r]);
    if (n16 == 0) Pl[gq2] = lrb[r];
  }
}

// Merge KSPLIT bf16 partials per q-row -> bf16 O [4096][320]
__global__ __launch_bounds__(256) void attn_merge(
    const float* __restrict__ Pl, const ushort_t* __restrict__ Pacc,
    ushort_t* __restrict__ O)
{
  int idx = blockIdx.x*256 + threadIdx.x;   // 0..32767
  int bh = idx >> 11, qi = idx & (LQ-1);
  int b = bh >> 3, h = bh & 7;
  float L = 0.f;
#pragma unroll
  for (int k = 0; k < KSPLIT; ++k) L += Pl[(size_t)k*NQROWS + idx];
  float inv = 1.0f / L;
  ushort_t* orow = O + (size_t)(b*LQ + qi)*DIM + h*HD;
#pragma unroll
  for (int u = 0; u < 5; ++u) {           // 5 chunks of 8 cols
    float acc[8] = {0,0,0,0,0,0,0,0};
#pragma unroll
    for (int k = 0; k < KSPLIT; ++k) {
      const ushort_t* pr = Pacc + ((size_t)k*NQROWS + idx)*40 + u*8;
      ushort_t vbuf[8];
      *(uint4*)vbuf = *(const uint4*)pr;
#pragma unroll
      for (int j = 0; j < 8; ++j) acc[j] += bf2f(vbuf[j]);
    }
    ushort_t ob[8];
#pragma unroll
    for (int j = 0; j < 8; ++j) ob[j] = f2bf(acc[j]*inv);
    *(uint4*)(orow + u*8) = *(uint4*)ob;
  }
}

extern "C" void kernel_launch(void* const* d_in, const int* in_sizes, int n_in,
                              void* d_out, int out_size, void* d_ws, size_t ws_size,
                              hipStream_t stream) {
  const float* hidden = (const float*)d_in[0];
  // d_in[1] encoder_hidden_states: UNUSED (softmax rows sum to 1 -> cross == vH)
  const float* ln1_g = (const float*)d_in[2];
  const float* ln1_b = (const float*)d_in[3];
  const float* wq1   = (const float*)d_in[4];
  const float* wk1   = (const float*)d_in[5];
  const float* wv1   = (const float*)d_in[6];
  const float* wo1   = (const float*)d_in[7];
  const float* bo1   = (const float*)d_in[8];
  const float* ln2_g = (const float*)d_in[9];
  const float* ln2_b = (const float*)d_in[10];
  // d_in[11] wq2, d_in[12] wk2: UNUSED
  const float* wvh   = (const float*)d_in[13];
  const float* wo2   = (const float*)d_in[14];
  const float* bo2   = (const float*)d_in[15];
  const float* ln3_g = (const float*)d_in[16];
  const float* ln3_b = (const float*)d_in[17];
  const float* wff1  = (const float*)d_in[18];
  const float* bff1  = (const float*)d_in[19];
  const float* wff2  = (const float*)d_in[20];
  const float* bff2  = (const float*)d_in[21];
  float* out = (float*)d_out;

  // workspace: bf16 region (shorts) then fp32 region
  ushort_t* wsu = (ushort_t*)d_ws;
  ushort_t* wbf   = wsu;                          // WBF_TOTAL shorts
  ushort_t* lnb   = wbf + WBF_TOTAL;              // 4096*320
  ushort_t* qkvb  = lnb + (size_t)MROWS*DIM;      // 4096*960
  ushort_t* attnb = qkvb + (size_t)MROWS*3*DIM;   // 4096*320
  ushort_t* gegb  = attnb + (size_t)MROWS*DIM;    // 4096*1280
  ushort_t* wct   = gegb + (size_t)MROWS*FFD;     // 320*320
  ushort_t* vtb   = wct + 320*320;                // 16*48*2048
  ushort_t* kpb   = vtb + (size_t)16*48*2048;     // 16*2048*64
  ushort_t* Pacc  = kpb + (size_t)16*2048*64;     // KSPLIT*32768*40 bf16
  float* fws = (float*)(Pacc + (size_t)KSPLIT*NQROWS*40 + 64);
  float* h1   = fws;                              // 4096*320
  float* h2   = h1 + (size_t)MROWS*DIM;
  float* Pl   = h2 + (size_t)MROWS*DIM;           // KSPLIT*32768

  dim3 t256(256);
  dim3 gconv(800, 8);
  dim3 gqkv(15, 32);     // N=960, 128-row tiles -> 480 blocks
  dim3 g320(5, 64);      // N=320, 64-row tiles -> 320 blocks
  dim3 gwc(5, 5);        // 320x320
  dim3 gffg(20, 32);     // ff1+geglu, 128-row tiles -> 640 blocks
  dim3 gvt(32, 16);
  dim3 gattn(16*4*16*KSPLIT);   // flat 4096 one-wave blocks, XCD swizzle inside

  convw_kernel<<<gconv, t256, 0, stream>>>(wq1, wk1, wv1, wo1, wo2, wff1, wff2, wvh, wbf);
  // Wc^T = wo2^T @ wvh^T (tiny)
  mgemm<<<gwc, t256, 0, stream>>>(wbf + OFF_WO2T, DIM, wbf + OFF_WVHB, DIM,
                                  nullptr, nullptr, nullptr, wct, DIM, DIM);

  // Stage 1: self-attention
  ln_kernel<<<MROWS/4, t256, 0, stream>>>(hidden, ln1_g, ln1_b, lnb);
  mgemm128<<<gqkv, t256, 0, stream>>>(lnb, DIM, wbf + OFF_WQKVT, DIM,
                                      qkvb, 3*DIM, DIM);
  vt_kernel<<<gvt, t256, 0, stream>>>(qkvb, vtb, kpb);
  attn_mfma<<<gattn, dim3(64), 0, stream>>>(qkvb, kpb, vtb, Pl, Pacc);
  attn_merge<<<NQROWS/256, t256, 0, stream>>>(Pl, Pacc, attnb);
  mgemm<<<g320, t256, 0, stream>>>(attnb, DIM, wbf + OFF_WO1T, DIM, bo1, hidden,
                                   h1, nullptr, DIM, DIM);

  // Stage 2: cross == ln2(h1) @ (wvh@wo2) + bo2 + h1   (softmax sums to 1)
  ln_kernel<<<MROWS/4, t256, 0, stream>>>(h1, ln2_g, ln2_b, lnb);
  mgemm<<<g320, t256, 0, stream>>>(lnb, DIM, wct, DIM, bo2, h1,
                                   h2, nullptr, DIM, DIM);

  // Stage 3: GEGLU FF
  ln_kernel<<<MROWS/4, t256, 0, stream>>>(h2, ln3_g, ln3_b, lnb);
  ff1_geglu<<<gffg, t256, 0, stream>>>(lnb, wbf + OFF_WFF1T, bff1, gegb);
  mgemm<<<g320, t256, 0, stream>>>(gegb, FFD, wbf + OFF_WFF2T, FFD, bff2, h2,
                                   out, nullptr, DIM, FFD);
}

// Round 13
// 253.210 us; speedup vs baseline: 1.0857x; 1.0857x over previous
//
#include <hip/hip_runtime.h>
#include <math.h>

// Problem constants
#define DIM   320
#define HD    40
#define NH    8
#define LQ    2048
#define BATCH 2
#define MROWS 4096
#define FFD   1280
#define FF2   2560

#define KSPLIT 4
#define KCHUNK (LQ/KSPLIT) // 512
#define KT     32
#define NQROWS (BATCH*NH*LQ)  // 32768

#define LSCALE (0.15811388300841897f * 1.4426950408889634f)

typedef unsigned short ushort_t;
using bf16x8 = __attribute__((ext_vector_type(8))) short;
using f32x4  = __attribute__((ext_vector_type(4))) float;

static __device__ inline ushort_t f2bf(float f) {
  union { float f; unsigned u; } x{f};
  unsigned r = x.u + 0x7FFFu + ((x.u >> 16) & 1u);
  return (ushort_t)(r >> 16);
}
static __device__ inline float bf2f(ushort_t h) {
  union { unsigned u; float f; } x; x.u = ((unsigned)h) << 16; return x.f;
}

#if __has_builtin(__builtin_amdgcn_exp2f)
#define EXP2F(x) __builtin_amdgcn_exp2f(x)
#else
#define EXP2F(x) exp2f(x)
#endif

// ---------------- LayerNorm: one wave per row of 320, bf16 out ---------------
__global__ __launch_bounds__(256) void ln_kernel(
    const float* __restrict__ X, const float* __restrict__ g,
    const float* __restrict__ bta, ushort_t* __restrict__ Y)
{
  int row  = blockIdx.x * 4 + (threadIdx.x >> 6);
  int lane = threadIdx.x & 63;
  const float* x = X + (size_t)row * DIM;
  float v[5];
  float s = 0.f;
#pragma unroll
  for (int i = 0; i < 5; ++i) { v[i] = x[lane + 64*i]; s += v[i]; }
#pragma unroll
  for (int off = 32; off >= 1; off >>= 1) s += __shfl_xor(s, off, 64);
  float mean = s * (1.0f/DIM);
  float sq = 0.f;
#pragma unroll
  for (int i = 0; i < 5; ++i) { float d = v[i] - mean; sq += d*d; }
#pragma unroll
  for (int off = 32; off >= 1; off >>= 1) sq += __shfl_xor(sq, off, 64);
  float rstd = rsqrtf(sq*(1.0f/DIM) + 1e-5f);
  ushort_t* y = Y + (size_t)row * DIM;
#pragma unroll
  for (int i = 0; i < 5; ++i) {
    int c = lane + 64*i;
    y[c] = f2bf((v[i]-mean)*rstd*g[c] + bta[c]);
  }
}

// ---------------- Weight convert/transpose to bf16, k-fastest ---------------
#define OFF_WQKVT 0
#define OFF_WO1T  (960*320)
#define OFF_WO2T  (OFF_WO1T + 320*320)
#define OFF_WFF1T (OFF_WO2T + 320*320)
#define OFF_WFF2T (OFF_WFF1T + 320*2560)
#define OFF_WVHB  (OFF_WFF2T + 1280*320)
#define WBF_TOTAL (OFF_WVHB + 320*320)

__global__ __launch_bounds__(256) void convw_kernel(
    const float* __restrict__ wq1, const float* __restrict__ wk1,
    const float* __restrict__ wv1, const float* __restrict__ wo1,
    const float* __restrict__ wo2, const float* __restrict__ wff1,
    const float* __restrict__ wff2, const float* __restrict__ wvh,
    ushort_t* __restrict__ dst)
{
  int e = blockIdx.y;
  const float* src; int K, N; size_t doff; int tr = 1; float scale = 1.f;
  switch (e) {
    case 0: src=wq1;  K=320;  N=320;  doff=OFF_WQKVT; scale=LSCALE; break;
    case 1: src=wk1;  K=320;  N=320;  doff=OFF_WQKVT + 320*320;  break;
    case 2: src=wv1;  K=320;  N=320;  doff=OFF_WQKVT + 2*320*320;break;
    case 3: src=wo1;  K=320;  N=320;  doff=OFF_WO1T;             break;
    case 4: src=wo2;  K=320;  N=320;  doff=OFF_WO2T;             break;
    case 5: src=wff1; K=320;  N=2560; doff=OFF_WFF1T;            break;
    case 6: src=wff2; K=1280; N=320;  doff=OFF_WFF2T;            break;
    default: src=wvh; K=320;  N=320;  doff=OFF_WVHB; tr=0;       break;
  }
  int ntN = N/32;
  int nt_total = (K/32)*ntN;
  int t = blockIdx.x;
  if (t >= nt_total) return;
  int kt = t / ntN, nt = t - kt*ntN;
  __shared__ float tile[32][33];
  int tx = threadIdx.x & 31, ty = threadIdx.x >> 5;
  ushort_t* d = dst + doff;
#pragma unroll
  for (int i = 0; i < 4; ++i) {
    int r = ty + 8*i;
    tile[r][tx] = src[(size_t)(kt*32+r)*N + nt*32+tx] * scale;
  }
  __syncthreads();
  if (tr) {
#pragma unroll
    for (int i = 0; i < 4; ++i) {
      int r = ty + 8*i;
      d[(size_t)(nt*32+r)*K + kt*32+tx] = f2bf(tile[tx][r]);
    }
  } else {
#pragma unroll
    for (int i = 0; i < 4; ++i) {
      int r = ty + 8*i;
      d[(size_t)(kt*32+r)*N + nt*32+tx] = f2bf(tile[r][tx]);
    }
  }
}

// ---- K/V repack: qkv [4096][960] -> Kp[16][2048][64] (d-pad 0) and
//      Vt[16][48][2048] (transposed, d-pad rows 0). Grid (32, 16).
__global__ __launch_bounds__(256) void vt_kernel(
    const ushort_t* __restrict__ qkv, ushort_t* __restrict__ Vt,
    ushort_t* __restrict__ Kp)
{
  int bh = blockIdx.y;
  int kt = blockIdx.x;
  int b = bh >> 3, h = bh & 7;
  int tid = threadIdx.x;
  __shared__ ushort_t tile[64*42];

  const ushort_t* ksrc = qkv + (size_t)(b*LQ + kt*64)*960 + DIM + h*HD;
  ushort_t* kdst = Kp + ((size_t)bh*2048 + (size_t)kt*64)*64;
#pragma unroll
  for (int i = 0; i < 2; ++i) {
    int f = i*256 + tid;
    if (f < 320) {
      int r = f/5, s = f - 5*r;
      *(uint4*)(kdst + r*64 + s*8) = *(const uint4*)(ksrc + (size_t)r*960 + s*8);
    }
  }
  if (tid < 192) {
    int r = tid/3, s = tid - 3*r;
    uint4 z = {0,0,0,0};
    *(uint4*)(kdst + r*64 + 40 + s*8) = z;
  }

  const ushort_t* vsrc = qkv + (size_t)(b*LQ + kt*64)*960 + 2*DIM + h*HD;
#pragma unroll
  for (int i = 0; i < 5; ++i) {
    int f = i*256 + tid;
    int r = f/20, c2 = f - r*20;
    *(unsigned*)(tile + r*42 + c2*2) = *(const unsigned*)(vsrc + (size_t)r*960 + c2*2);
  }
  __syncthreads();
  ushort_t* dstp = Vt + (size_t)bh*48*2048 + kt*64;
#pragma unroll
  for (int i = 0; i < 6; ++i) {
    int f = i*256 + tid;
    int dd = f >> 5, kk = f & 31;
    unsigned val = 0;
    if (dd < 40) {
      unsigned lo = tile[(kk*2)*42 + dd];
      unsigned hi = tile[(kk*2+1)*42 + dd];
      val = lo | (hi << 16);
    }
    *(unsigned*)(dstp + (size_t)dd*2048 + kk*2) = val;
  }
}

// ---------------- bf16 MFMA GEMM (TN), 64x64 tile, BK=64, reg prefetch ------
// BK=64: 5 K-iterations instead of 10; 8 MFMA per wave between barriers
// instead of 4 (the N=320 GEMMs were barrier-dominated at BK=32).
#define AST 72   // 64 k + 8 pad shorts: 36-dword rows -> 2-way bank (free)
__global__ __launch_bounds__(256) void mgemm(
    const ushort_t* __restrict__ A, int lda,
    const ushort_t* __restrict__ Bt, int ldb,
    const float* __restrict__ bias,
    const float* __restrict__ R,
    float* __restrict__ Cf, ushort_t* __restrict__ Cb, int ldc,
    int K)
{
  __shared__ ushort_t As[64*AST];
  __shared__ ushort_t Bs[64*AST];
  int tid = threadIdx.x;
  int w = tid >> 6, lane = tid & 63, quad = lane >> 4, n16 = lane & 15;
  int wm = w >> 1, wn = w & 1;
  int bm = blockIdx.y * 64, bn = blockIdx.x * 64;
  int sr = tid >> 2, sc = (tid & 3) << 4;   // 64 rows x 4 threads x 16 shorts
  const ushort_t* Ag = A  + (size_t)(bm + sr)*lda + sc;
  const ushort_t* Bg = Bt + (size_t)(bn + sr)*ldb + sc;

  f32x4 acc00 = {0.f,0.f,0.f,0.f}, acc01 = acc00, acc10 = acc00, acc11 = acc00;

  float4 av0 = *(const float4*)(Ag);
  float4 av1 = *(const float4*)(Ag + 8);
  float4 bv0 = *(const float4*)(Bg);
  float4 bv1 = *(const float4*)(Bg + 8);
  for (int k0 = 0; k0 < K; k0 += 64) {
    __syncthreads();
    *(float4*)(As + sr*AST + sc)     = av0;
    *(float4*)(As + sr*AST + sc + 8) = av1;
    *(float4*)(Bs + sr*AST + sc)     = bv0;
    *(float4*)(Bs + sr*AST + sc + 8) = bv1;
    __syncthreads();
    if (k0 + 64 < K) {
      av0 = *(const float4*)(Ag + k0 + 64);
      av1 = *(const float4*)(Ag + k0 + 72);
      bv0 = *(const float4*)(Bg + k0 + 64);
      bv1 = *(const float4*)(Bg + k0 + 72);
    }
#pragma unroll
    for (int kk = 0; kk < 64; kk += 32) {
      bf16x8 fa0 = *(const bf16x8*)(As + (wm*32 +      n16)*AST + kk + quad*8);
      bf16x8 fa1 = *(const bf16x8*)(As + (wm*32 + 16 + n16)*AST + kk + quad*8);
      bf16x8 fb0 = *(const bf16x8*)(Bs + (wn*32 +      n16)*AST + kk + quad*8);
      bf16x8 fb1 = *(const bf16x8*)(Bs + (wn*32 + 16 + n16)*AST + kk + quad*8);
      acc00 = __builtin_amdgcn_mfma_f32_16x16x32_bf16(fa0, fb0, acc00, 0,0,0);
      acc01 = __builtin_amdgcn_mfma_f32_16x16x32_bf16(fa0, fb1, acc01, 0,0,0);
      acc10 = __builtin_amdgcn_mfma_f32_16x16x32_bf16(fa1, fb0, acc10, 0,0,0);
      acc11 = __builtin_amdgcn_mfma_f32_16x16x32_bf16(fa1, fb1, acc11, 0,0,0);
    }
  }

  f32x4 accs[2][2] = {{acc00, acc01},{acc10, acc11}};
#pragma unroll
  for (int s = 0; s < 2; ++s)
#pragma unroll
    for (int t = 0; t < 2; ++t) {
      int c = bn + wn*32 + t*16 + n16;
      float bb = bias ? bias[c] : 0.f;
#pragma unroll
      for (int i = 0; i < 4; ++i) {
        int r = bm + wm*32 + s*16 + quad*4 + i;
        float v = accs[s][t][i] + bb;
        if (R)  v += R[(size_t)r*ldc + c];
        if (Cf) Cf[(size_t)r*ldc + c] = v;
        if (Cb) Cb[(size_t)r*ldc + c] = f2bf(v);
      }
    }
}

// ---------------- bf16 MFMA GEMM (TN), 128x64 tile — for N>=960 -------------
#define AS_STRIDE 40
__global__ __launch_bounds__(256) void mgemm128(
    const ushort_t* __restrict__ A, int lda,
    const ushort_t* __restrict__ Bt, int ldb,
    ushort_t* __restrict__ Cb, int ldc, int K)
{
  __shared__ ushort_t As[128*AS_STRIDE];   // 10 KB
  __shared__ ushort_t Bs[64*AS_STRIDE];    // 5 KB
  int tid = threadIdx.x;
  int w = tid >> 6, lane = tid & 63, quad = lane >> 4, n16 = lane & 15;
  int wm = w >> 1, wn = w & 1;
  int bm = blockIdx.y * 128, bn = blockIdx.x * 64;
  int ar = tid >> 1, ac = (tid & 1) << 4;
  int br = tid >> 2, bc = (tid & 3) << 3;
  const ushort_t* Ag = A  + (size_t)(bm + ar)*lda + ac;
  const ushort_t* Bg = Bt + (size_t)(bn + br)*ldb + bc;

  f32x4 acc[4][2];
#pragma unroll
  for (int s = 0; s < 4; ++s)
#pragma unroll
    for (int t = 0; t < 2; ++t) acc[s][t] = f32x4{0.f,0.f,0.f,0.f};

  float4 av0 = *(const float4*)(Ag);
  float4 av1 = *(const float4*)(Ag + 8);
  float4 bv  = *(const float4*)(Bg);
  for (int k0 = 0; k0 < K; k0 += 32) {
    __syncthreads();
    *(float4*)(As + ar*AS_STRIDE + ac)     = av0;
    *(float4*)(As + ar*AS_STRIDE + ac + 8) = av1;
    *(float4*)(Bs + br*AS_STRIDE + bc)     = bv;
    __syncthreads();
    if (k0 + 32 < K) {
      av0 = *(const float4*)(Ag + k0 + 32);
      av1 = *(const float4*)(Ag + k0 + 40);
      bv  = *(const float4*)(Bg + k0 + 32);
    }
    bf16x8 fa[4], fb[2];
#pragma unroll
    for (int s = 0; s < 4; ++s)
      fa[s] = *(const bf16x8*)(As + (wm*64 + s*16 + n16)*AS_STRIDE + quad*8);
#pragma unroll
    for (int t = 0; t < 2; ++t)
      fb[t] = *(const bf16x8*)(Bs + (wn*32 + t*16 + n16)*AS_STRIDE + quad*8);
#pragma unroll
    for (int s = 0; s < 4; ++s)
#pragma unroll
      for (int t = 0; t < 2; ++t)
        acc[s][t] = __builtin_amdgcn_mfma_f32_16x16x32_bf16(fa[s], fb[t], acc[s][t], 0,0,0);
  }

#pragma unroll
  for (int s = 0; s < 4; ++s)
#pragma unroll
    for (int t = 0; t < 2; ++t) {
      int c = bn + wn*32 + t*16 + n16;
#pragma unroll
      for (int i = 0; i < 4; ++i) {
        int r = bm + wm*64 + s*16 + quad*4 + i;
        Cb[(size_t)r*ldc + c] = f2bf(acc[s][t][i]);
      }
    }
}

// -------- ff1 GEMM 128x64 + fused GEGLU: gegb = x * gelu(gate) --------------
__global__ __launch_bounds__(256) void ff1_geglu(
    const ushort_t* __restrict__ A, const ushort_t* __restrict__ Bt,
    const float* __restrict__ bias, ushort_t* __restrict__ Og)
{
  __shared__ ushort_t As[128*AS_STRIDE];
  __shared__ ushort_t Bxs[64*AS_STRIDE];
  __shared__ ushort_t Bgs[64*AS_STRIDE];
  int tid = threadIdx.x;
  int w = tid >> 6, lane = tid & 63, quad = lane >> 4, n16 = lane & 15;
  int wm = w >> 1, wn = w & 1;
  int bm = blockIdx.y * 128, bn = blockIdx.x * 64;
  int ar = tid >> 1, ac = (tid & 1) << 4;
  int br = tid >> 2, bc = (tid & 3) << 3;
  const ushort_t* Ag  = A  + (size_t)(bm + ar)*DIM + ac;
  const ushort_t* Bxg = Bt + (size_t)(bn + br)*DIM + bc;
  const ushort_t* Bgg = Bt + (size_t)(bn + FFD + br)*DIM + bc;

  f32x4 ax[4][2], ag[4][2];
#pragma unroll
  for (int s = 0; s < 4; ++s)
#pragma unroll
    for (int t = 0; t < 2; ++t) { ax[s][t] = f32x4{0.f,0.f,0.f,0.f}; ag[s][t] = ax[s][t]; }

  float4 av0 = *(const float4*)(Ag);
  float4 av1 = *(const float4*)(Ag + 8);
  float4 bxv = *(const float4*)(Bxg);
  float4 bgv = *(const float4*)(Bgg);
  for (int k0 = 0; k0 < DIM; k0 += 32) {
    __syncthreads();
    *(float4*)(As  + ar*AS_STRIDE + ac)     = av0;
    *(float4*)(As  + ar*AS_STRIDE + ac + 8) = av1;
    *(float4*)(Bxs + br*AS_STRIDE + bc)     = bxv;
    *(float4*)(Bgs + br*AS_STRIDE + bc)     = bgv;
    __syncthreads();
    if (k0 + 32 < DIM) {
      av0 = *(const float4*)(Ag  + k0 + 32);
      av1 = *(const float4*)(Ag  + k0 + 40);
      bxv = *(const float4*)(Bxg + k0 + 32);
      bgv = *(const float4*)(Bgg + k0 + 32);
    }
    bf16x8 fa[4], fx[2], fg[2];
#pragma unroll
    for (int s = 0; s < 4; ++s)
      fa[s] = *(const bf16x8*)(As + (wm*64 + s*16 + n16)*AS_STRIDE + quad*8);
#pragma unroll
    for (int t = 0; t < 2; ++t) {
      fx[t] = *(const bf16x8*)(Bxs + (wn*32 + t*16 + n16)*AS_STRIDE + quad*8);
      fg[t] = *(const bf16x8*)(Bgs + (wn*32 + t*16 + n16)*AS_STRIDE + quad*8);
    }
#pragma unroll
    for (int s = 0; s < 4; ++s)
#pragma unroll
      for (int t = 0; t < 2; ++t) {
        ax[s][t] = __builtin_amdgcn_mfma_f32_16x16x32_bf16(fa[s], fx[t], ax[s][t], 0,0,0);
        ag[s][t] = __builtin_amdgcn_mfma_f32_16x16x32_bf16(fa[s], fg[t], ag[s][t], 0,0,0);
      }
  }

  const float kk = 0.7071067811865476f;
#pragma unroll
  for (int s = 0; s < 4; ++s)
#pragma unroll
    for (int t = 0; t < 2; ++t) {
      int c = bn + wn*32 + t*16 + n16;
      float bx = bias[c], bg = bias[c + FFD];
#pragma unroll
      for (int i = 0; i < 4; ++i) {
        int r = bm + wm*64 + s*16 + quad*4 + i;
        float xx = ax[s][t][i] + bx;
        float gg = ag[s][t][i] + bg;
        Og[(size_t)r*FFD + c] = f2bf(xx * 0.5f * gg * (1.f + erff(gg * kk)));
      }
    }
}

// ---------------- MFMA flash attention: 1-wave blocks, fixed-max ------------
// 1-wave blocks pack more waves/SIMD than (256,2) 4-wave blocks (R12:
// Occupancy 26->38%). launch_bounds(64,2): 256-VGPR cap so the allocator
// lands at the natural ~84 — R12's (64,4) forced 64 VGPR and spilled 60 MB.
// Q pre-scaled via wq1. Kp[bh][2048][64], Vt[bh][48][2048]. XCD swizzle on
// low grid bits (R10: FETCH 31->6.7 MB). bf16 partials (R11).
#define PS_STRIDE 40

__global__ __launch_bounds__(64, 2) void attn_mfma(
    const ushort_t* __restrict__ qkv, const ushort_t* __restrict__ Kp,
    const ushort_t* __restrict__ Vt,
    float* __restrict__ Pl, ushort_t* __restrict__ Pacc)
{
  __shared__ ushort_t Psw[32*PS_STRIDE];
  int lane = threadIdx.x & 63;
  int quad = lane >> 4;
  int n16  = lane & 15;

  int blk  = blockIdx.x;
  int bh   = (blk & 7) | (((blk >> 3) & 1) << 3);
  int rest = blk >> 4;            // 0..255
  int w    = rest & 3;
  int qt   = (rest >> 2) & 15;
  int ks   = rest >> 6;           // 0..3
  int b = bh >> 3, h = bh & 7;

  const ushort_t* qrowa = qkv + (size_t)(b*LQ + qt*128 + w*32 + n16)*960 + h*HD;
  const ushort_t* qrowb = qrowa + 16*960;
  bf16x8 qf0a = *(const bf16x8*)(qrowa + quad*8);
  bf16x8 qf1a = *(const bf16x8*)(qrowa + 32);  // quads>0: garbage x Kp-pad(0) = 0
  bf16x8 qf0b = *(const bf16x8*)(qrowb + quad*8);
  bf16x8 qf1b = *(const bf16x8*)(qrowb + 32);

  const ushort_t* Kh = Kp + (size_t)bh*2048*64;
  const ushort_t* Vh = Vt + (size_t)bh*48*2048;
  int k0 = ks*KCHUNK;
  int koff0 = n16*64 + quad*8;
  int koff1 = (16+n16)*64 + quad*8;
  int voff = quad*8;

  f32x4 o0a = {0.f,0.f,0.f,0.f}, o1a = o0a, o2a = o0a;
  f32x4 o0b = o0a, o1b = o0a, o2b = o0a;
  f32x4 la0a = o0a, la1a = o0a, la0b = o0a, la1b = o0a;

#define LOAD_TILE(T0, K00,K01,K10,K11,V0,V1,V2) { \
  const ushort_t* Kt_ = Kh + (size_t)(k0 + (T0))*64; \
  const ushort_t* Vt_ = Vh + k0 + (T0); \
  K00 = *(const bf16x8*)(Kt_ + koff0); \
  K01 = *(const bf16x8*)(Kt_ + koff0 + 32); \
  K10 = *(const bf16x8*)(Kt_ + koff1); \
  K11 = *(const bf16x8*)(Kt_ + koff1 + 32); \
  V0 = *(const bf16x8*)(Vt_ + (size_t)(n16)*2048 + voff); \
  V1 = *(const bf16x8*)(Vt_ + (size_t)(16+n16)*2048 + voff); \
  V2 = *(const bf16x8*)(Vt_ + (size_t)(32+n16)*2048 + voff); }

#define COMPUTE(K00,K01,K10,K11,V0,V1,V2) { \
  f32x4 s0a = {-8.f,-8.f,-8.f,-8.f}; f32x4 s1a = s0a, s0b = s0a, s1b = s0a; \
  s0a = __builtin_amdgcn_mfma_f32_16x16x32_bf16(qf0a, K00, s0a, 0,0,0); \
  s1a = __builtin_amdgcn_mfma_f32_16x16x32_bf16(qf0a, K10, s1a, 0,0,0); \
  s0b = __builtin_amdgcn_mfma_f32_16x16x32_bf16(qf0b, K00, s0b, 0,0,0); \
  s1b = __builtin_amdgcn_mfma_f32_16x16x32_bf16(qf0b, K10, s1b, 0,0,0); \
  s0a = __builtin_amdgcn_mfma_f32_16x16x32_bf16(qf1a, K01, s0a, 0,0,0); \
  s1a = __builtin_amdgcn_mfma_f32_16x16x32_bf16(qf1a, K11, s1a, 0,0,0); \
  s0b = __builtin_amdgcn_mfma_f32_16x16x32_bf16(qf1b, K01, s0b, 0,0,0); \
  s1b = __builtin_amdgcn_mfma_f32_16x16x32_bf16(qf1b, K11, s1b, 0,0,0); \
  f32x4 p0a, p1a, p0b, p1b; \
  _Pragma("unroll") \
  for (int r = 0; r < 4; ++r) { \
    p0a[r] = EXP2F(s0a[r]); p1a[r] = EXP2F(s1a[r]); \
    p0b[r] = EXP2F(s0b[r]); p1b[r] = EXP2F(s1b[r]); \
  } \
  la0a += p0a; la1a += p1a; la0b += p0b; la1b += p1b; \
  _Pragma("unroll") \
  for (int r = 0; r < 4; ++r) { \
    int row = quad*4 + r; \
    Psw[row*PS_STRIDE + n16]           = (ushort_t)(__float_as_uint(p0a[r]) >> 16); \
    Psw[row*PS_STRIDE + 16 + n16]      = (ushort_t)(__float_as_uint(p1a[r]) >> 16); \
    Psw[(16+row)*PS_STRIDE + n16]      = (ushort_t)(__float_as_uint(p0b[r]) >> 16); \
    Psw[(16+row)*PS_STRIDE + 16 + n16] = (ushort_t)(__float_as_uint(p1b[r]) >> 16); \
  } \
  bf16x8 paa = *(const bf16x8*)(Psw + n16*PS_STRIDE + quad*8); \
  bf16x8 pab = *(const bf16x8*)(Psw + (16+n16)*PS_STRIDE + quad*8); \
  o0a = __builtin_amdgcn_mfma_f32_16x16x32_bf16(paa, V0, o0a, 0,0,0); \
  o0b = __builtin_amdgcn_mfma_f32_16x16x32_bf16(pab, V0, o0b, 0,0,0); \
  o1a = __builtin_amdgcn_mfma_f32_16x16x32_bf16(paa, V1, o1a, 0,0,0); \
  o1b = __builtin_amdgcn_mfma_f32_16x16x32_bf16(pab, V1, o1b, 0,0,0); \
  o2a = __builtin_amdgcn_mfma_f32_16x16x32_bf16(paa, V2, o2a, 0,0,0); \
  o2b = __builtin_amdgcn_mfma_f32_16x16x32_bf16(pab, V2, o2b, 0,0,0); }

  bf16x8 ka0,ka1,ka2,ka3,va0,va1,va2;
  bf16x8 kb0,kb1,kb2,kb3,vb0,vb1,vb2;
  LOAD_TILE(0, ka0,ka1,ka2,ka3,va0,va1,va2);
  for (int t0 = 0; t0 < KCHUNK; t0 += 2*KT) {
    LOAD_TILE(t0 + KT, kb0,kb1,kb2,kb3,vb0,vb1,vb2);
    COMPUTE(ka0,ka1,ka2,ka3,va0,va1,va2);
    if (t0 + 2*KT < KCHUNK) {
      LOAD_TILE(t0 + 2*KT, ka0,ka1,ka2,ka3,va0,va1,va2);
    }
    COMPUTE(kb0,kb1,kb2,kb3,vb0,vb1,vb2);
  }
#undef LOAD_TILE
#undef COMPUTE

  float lra[4], lrb[4];
#pragma unroll
  for (int r = 0; r < 4; ++r) { lra[r] = la0a[r] + la1a[r]; lrb[r] = la0b[r] + la1b[r]; }
#pragma unroll
  for (int off = 1; off < 16; off <<= 1)
#pragma unroll
    for (int r = 0; r < 4; ++r) {
      lra[r] += __shfl_xor(lra[r], off, 64);
      lrb[r] += __shfl_xor(lrb[r], off, 64);
    }

  int gqa = bh*LQ + qt*128 + w*32 + quad*4;
  size_t base = (size_t)ks*NQROWS;
#pragma unroll
  for (int r = 0; r < 4; ++r) {
    size_t gq = base + gqa + r;
    ushort_t* pw = Pacc + gq*40;
    pw[n16]      = f2bf(o0a[r]);
    pw[16 + n16] = f2bf(o1a[r]);
    if (n16 < 8) pw[32 + n16] = f2bf(o2a[r]);
    if (n16 == 0) Pl[gq] = lra[r];
    size_t gq2 = gq + 16;
    ushort_t* pw2 = Pacc + gq2*40;
    pw2[n16]      = f2bf(o0b[r]);
    pw2[16 + n16] = f2bf(o1b[r]);
    if (n16 < 8) pw2[32 + n16] = f2bf(o2b[r]);
    if (n16 == 0) Pl[gq2] = lrb[r];
  }
}

// Merge KSPLIT bf16 partials per q-row -> bf16 O [4096][320]
__global__ __launch_bounds__(256) void attn_merge(
    const float* __restrict__ Pl, const ushort_t* __restrict__ Pacc,
    ushort_t* __restrict__ O)
{
  int idx = blockIdx.x*256 + threadIdx.x;   // 0..32767
  int bh = idx >> 11, qi = idx & (LQ-1);
  int b = bh >> 3, h = bh & 7;
  float L = 0.f;
#pragma unroll
  for (int k = 0; k < KSPLIT; ++k) L += Pl[(size_t)k*NQROWS + idx];
  float inv = 1.0f / L;
  ushort_t* orow = O + (size_t)(b*LQ + qi)*DIM + h*HD;
#pragma unroll
  for (int u = 0; u < 5; ++u) {           // 5 chunks of 8 cols
    float acc[8] = {0,0,0,0,0,0,0,0};
#pragma unroll
    for (int k = 0; k < KSPLIT; ++k) {
      const ushort_t* pr = Pacc + ((size_t)k*NQROWS + idx)*40 + u*8;
      ushort_t vbuf[8];
      *(uint4*)vbuf = *(const uint4*)pr;
#pragma unroll
      for (int j = 0; j < 8; ++j) acc[j] += bf2f(vbuf[j]);
    }
    ushort_t ob[8];
#pragma unroll
    for (int j = 0; j < 8; ++j) ob[j] = f2bf(acc[j]*inv);
    *(uint4*)(orow + u*8) = *(uint4*)ob;
  }
}

extern "C" void kernel_launch(void* const* d_in, const int* in_sizes, int n_in,
                              void* d_out, int out_size, void* d_ws, size_t ws_size,
                              hipStream_t stream) {
  const float* hidden = (const float*)d_in[0];
  // d_in[1] encoder_hidden_states: UNUSED (softmax rows sum to 1 -> cross == vH)
  const float* ln1_g = (const float*)d_in[2];
  const float* ln1_b = (const float*)d_in[3];
  const float* wq1   = (const float*)d_in[4];
  const float* wk1   = (const float*)d_in[5];
  const float* wv1   = (const float*)d_in[6];
  const float* wo1   = (const float*)d_in[7];
  const float* bo1   = (const float*)d_in[8];
  const float* ln2_g = (const float*)d_in[9];
  const float* ln2_b = (const float*)d_in[10];
  // d_in[11] wq2, d_in[12] wk2: UNUSED
  const float* wvh   = (const float*)d_in[13];
  const float* wo2   = (const float*)d_in[14];
  const float* bo2   = (const float*)d_in[15];
  const float* ln3_g = (const float*)d_in[16];
  const float* ln3_b = (const float*)d_in[17];
  const float* wff1  = (const float*)d_in[18];
  const float* bff1  = (const float*)d_in[19];
  const float* wff2  = (const float*)d_in[20];
  const float* bff2  = (const float*)d_in[21];
  float* out = (float*)d_out;

  // workspace: bf16 region (shorts) then fp32 region
  ushort_t* wsu = (ushort_t*)d_ws;
  ushort_t* wbf   = wsu;                          // WBF_TOTAL shorts
  ushort_t* lnb   = wbf + WBF_TOTAL;              // 4096*320
  ushort_t* qkvb  = lnb + (size_t)MROWS*DIM;      // 4096*960
  ushort_t* attnb = qkvb + (size_t)MROWS*3*DIM;   // 4096*320
  ushort_t* gegb  = attnb + (size_t)MROWS*DIM;    // 4096*1280
  ushort_t* wct   = gegb + (size_t)MROWS*FFD;     // 320*320
  ushort_t* vtb   = wct + 320*320;                // 16*48*2048
  ushort_t* kpb   = vtb + (size_t)16*48*2048;     // 16*2048*64
  ushort_t* Pacc  = kpb + (size_t)16*2048*64;     // KSPLIT*32768*40 bf16
  float* fws = (float*)(Pacc + (size_t)KSPLIT*NQROWS*40 + 64);
  float* h1   = fws;                              // 4096*320
  float* h2   = h1 + (size_t)MROWS*DIM;
  float* Pl   = h2 + (size_t)MROWS*DIM;           // KSPLIT*32768

  dim3 t256(256);
  dim3 gconv(800, 8);
  dim3 gqkv(15, 32);     // N=960, 128-row tiles -> 480 blocks
  dim3 g320(5, 64);      // N=320, 64-row tiles -> 320 blocks
  dim3 gwc(5, 5);        // 320x320
  dim3 gffg(20, 32);     // ff1+geglu, 128-row tiles -> 640 blocks
  dim3 gvt(32, 16);
  dim3 gattn(16*4*16*KSPLIT);   // flat 4096 one-wave blocks, XCD swizzle inside

  convw_kernel<<<gconv, t256, 0, stream>>>(wq1, wk1, wv1, wo1, wo2, wff1, wff2, wvh, wbf);
  // Wc^T = wo2^T @ wvh^T (tiny)
  mgemm<<<gwc, t256, 0, stream>>>(wbf + OFF_WO2T, DIM, wbf + OFF_WVHB, DIM,
                                  nullptr, nullptr, nullptr, wct, DIM, DIM);

  // Stage 1: self-attention
  ln_kernel<<<MROWS/4, t256, 0, stream>>>(hidden, ln1_g, ln1_b, lnb);
  mgemm128<<<gqkv, t256, 0, stream>>>(lnb, DIM, wbf + OFF_WQKVT, DIM,
                                      qkvb, 3*DIM, DIM);
  vt_kernel<<<gvt, t256, 0, stream>>>(qkvb, vtb, kpb);
  attn_mfma<<<gattn, dim3(64), 0, stream>>>(qkvb, kpb, vtb, Pl, Pacc);
  attn_merge<<<NQROWS/256, t256, 0, stream>>>(Pl, Pacc, attnb);
  mgemm<<<g320, t256, 0, stream>>>(attnb, DIM, wbf + OFF_WO1T, DIM, bo1, hidden,
                                   h1, nullptr, DIM, DIM);

  // Stage 2: cross == ln2(h1) @ (wvh@wo2) + bo2 + h1   (softmax sums to 1)
  ln_kernel<<<MROWS/4, t256, 0, stream>>>(h1, ln2_g, ln2_b, lnb);
  mgemm<<<g320, t256, 0, stream>>>(lnb, DIM, wct, DIM, bo2, h1,
                                   h2, nullptr, DIM, DIM);

  // Stage 3: GEGLU FF
  ln_kernel<<<MROWS/4, t256, 0, stream>>>(h2, ln3_g, ln3_b, lnb);
  ff1_geglu<<<gffg, t256, 0, stream>>>(lnb, wbf + OFF_WFF1T, bff1, gegb);
  mgemm<<<g320, t256, 0, stream>>>(gegb, FFD, wbf + OFF_WFF2T, FFD, bff2, h2,
                                   out, nullptr, DIM, FFD);
}

// Round 14
// 251.830 us; speedup vs baseline: 1.0916x; 1.0055x over previous
//
#include <hip/hip_runtime.h>
#include <math.h>

// Problem constants
#define DIM   320
#define HD    40
#define NH    8
#define LQ    2048
#define BATCH 2
#define MROWS 4096
#define FFD   1280
#define FF2   2560

#define KSPLIT 4
#define KCHUNK (LQ/KSPLIT) // 512
#define KT     32
#define NQROWS (BATCH*NH*LQ)  // 32768

#define LSCALE (0.15811388300841897f * 1.4426950408889634f)

typedef unsigned short ushort_t;
using bf16x8 = __attribute__((ext_vector_type(8))) short;
using f32x4  = __attribute__((ext_vector_type(4))) float;

static __device__ inline ushort_t f2bf(float f) {
  union { float f; unsigned u; } x{f};
  unsigned r = x.u + 0x7FFFu + ((x.u >> 16) & 1u);
  return (ushort_t)(r >> 16);
}
static __device__ inline float bf2f(ushort_t h) {
  union { unsigned u; float f; } x; x.u = ((unsigned)h) << 16; return x.f;
}

#if __has_builtin(__builtin_amdgcn_exp2f)
#define EXP2F(x) __builtin_amdgcn_exp2f(x)
#else
#define EXP2F(x) exp2f(x)
#endif

// ---------------- LayerNorm: one wave per row of 320, bf16 out ---------------
__global__ __launch_bounds__(256) void ln_kernel(
    const float* __restrict__ X, const float* __restrict__ g,
    const float* __restrict__ bta, ushort_t* __restrict__ Y)
{
  int row  = blockIdx.x * 4 + (threadIdx.x >> 6);
  int lane = threadIdx.x & 63;
  const float* x = X + (size_t)row * DIM;
  float v[5];
  float s = 0.f;
#pragma unroll
  for (int i = 0; i < 5; ++i) { v[i] = x[lane + 64*i]; s += v[i]; }
#pragma unroll
  for (int off = 32; off >= 1; off >>= 1) s += __shfl_xor(s, off, 64);
  float mean = s * (1.0f/DIM);
  float sq = 0.f;
#pragma unroll
  for (int i = 0; i < 5; ++i) { float d = v[i] - mean; sq += d*d; }
#pragma unroll
  for (int off = 32; off >= 1; off >>= 1) sq += __shfl_xor(sq, off, 64);
  float rstd = rsqrtf(sq*(1.0f/DIM) + 1e-5f);
  ushort_t* y = Y + (size_t)row * DIM;
#pragma unroll
  for (int i = 0; i < 5; ++i) {
    int c = lane + 64*i;
    y[c] = f2bf((v[i]-mean)*rstd*g[c] + bta[c]);
  }
}

// ---------------- Weight convert/transpose to bf16, k-fastest ---------------
#define OFF_WQKVT 0
#define OFF_WO1T  (960*320)
#define OFF_WO2T  (OFF_WO1T + 320*320)
#define OFF_WFF1T (OFF_WO2T + 320*320)
#define OFF_WFF2T (OFF_WFF1T + 320*2560)
#define OFF_WVHB  (OFF_WFF2T + 1280*320)
#define WBF_TOTAL (OFF_WVHB + 320*320)

__global__ __launch_bounds__(256) void convw_kernel(
    const float* __restrict__ wq1, const float* __restrict__ wk1,
    const float* __restrict__ wv1, const float* __restrict__ wo1,
    const float* __restrict__ wo2, const float* __restrict__ wff1,
    const float* __restrict__ wff2, const float* __restrict__ wvh,
    ushort_t* __restrict__ dst)
{
  int e = blockIdx.y;
  const float* src; int K, N; size_t doff; int tr = 1; float scale = 1.f;
  switch (e) {
    case 0: src=wq1;  K=320;  N=320;  doff=OFF_WQKVT; scale=LSCALE; break;
    case 1: src=wk1;  K=320;  N=320;  doff=OFF_WQKVT + 320*320;  break;
    case 2: src=wv1;  K=320;  N=320;  doff=OFF_WQKVT + 2*320*320;break;
    case 3: src=wo1;  K=320;  N=320;  doff=OFF_WO1T;             break;
    case 4: src=wo2;  K=320;  N=320;  doff=OFF_WO2T;             break;
    case 5: src=wff1; K=320;  N=2560; doff=OFF_WFF1T;            break;
    case 6: src=wff2; K=1280; N=320;  doff=OFF_WFF2T;            break;
    default: src=wvh; K=320;  N=320;  doff=OFF_WVHB; tr=0;       break;
  }
  int ntN = N/32;
  int nt_total = (K/32)*ntN;
  int t = blockIdx.x;
  if (t >= nt_total) return;
  int kt = t / ntN, nt = t - kt*ntN;
  __shared__ float tile[32][33];
  int tx = threadIdx.x & 31, ty = threadIdx.x >> 5;
  ushort_t* d = dst + doff;
#pragma unroll
  for (int i = 0; i < 4; ++i) {
    int r = ty + 8*i;
    tile[r][tx] = src[(size_t)(kt*32+r)*N + nt*32+tx] * scale;
  }
  __syncthreads();
  if (tr) {
#pragma unroll
    for (int i = 0; i < 4; ++i) {
      int r = ty + 8*i;
      d[(size_t)(nt*32+r)*K + kt*32+tx] = f2bf(tile[tx][r]);
    }
  } else {
#pragma unroll
    for (int i = 0; i < 4; ++i) {
      int r = ty + 8*i;
      d[(size_t)(kt*32+r)*N + nt*32+tx] = f2bf(tile[r][tx]);
    }
  }
}

// ---- K/V repack: qkv [4096][960] -> Kp[16][2048][64] (d-pad 0) and
//      Vt[16][48][2048] (transposed, d-pad rows 0). Grid (32, 16).
__global__ __launch_bounds__(256) void vt_kernel(
    const ushort_t* __restrict__ qkv, ushort_t* __restrict__ Vt,
    ushort_t* __restrict__ Kp)
{
  int bh = blockIdx.y;
  int kt = blockIdx.x;
  int b = bh >> 3, h = bh & 7;
  int tid = threadIdx.x;
  __shared__ ushort_t tile[64*42];

  const ushort_t* ksrc = qkv + (size_t)(b*LQ + kt*64)*960 + DIM + h*HD;
  ushort_t* kdst = Kp + ((size_t)bh*2048 + (size_t)kt*64)*64;
#pragma unroll
  for (int i = 0; i < 2; ++i) {
    int f = i*256 + tid;
    if (f < 320) {
      int r = f/5, s = f - 5*r;
      *(uint4*)(kdst + r*64 + s*8) = *(const uint4*)(ksrc + (size_t)r*960 + s*8);
    }
  }
  if (tid < 192) {
    int r = tid/3, s = tid - 3*r;
    uint4 z = {0,0,0,0};
    *(uint4*)(kdst + r*64 + 40 + s*8) = z;
  }

  const ushort_t* vsrc = qkv + (size_t)(b*LQ + kt*64)*960 + 2*DIM + h*HD;
#pragma unroll
  for (int i = 0; i < 5; ++i) {
    int f = i*256 + tid;
    int r = f/20, c2 = f - r*20;
    *(unsigned*)(tile + r*42 + c2*2) = *(const unsigned*)(vsrc + (size_t)r*960 + c2*2);
  }
  __syncthreads();
  ushort_t* dstp = Vt + (size_t)bh*48*2048 + kt*64;
#pragma unroll
  for (int i = 0; i < 6; ++i) {
    int f = i*256 + tid;
    int dd = f >> 5, kk = f & 31;
    unsigned val = 0;
    if (dd < 40) {
      unsigned lo = tile[(kk*2)*42 + dd];
      unsigned hi = tile[(kk*2+1)*42 + dd];
      val = lo | (hi << 16);
    }
    *(unsigned*)(dstp + (size_t)dd*2048 + kk*2) = val;
  }
}

// ---------------- bf16 MFMA GEMM (TN), 64x64 tile, BK=64, reg prefetch ------
// BK=64: 5 K-iterations instead of 10; 8 MFMA per wave between barriers
// (R13: rest -15 us vs BK=32).
#define AST 72   // 64 k + 8 pad shorts: 36-dword rows -> 2-way bank (free)
__global__ __launch_bounds__(256) void mgemm(
    const ushort_t* __restrict__ A, int lda,
    const ushort_t* __restrict__ Bt, int ldb,
    const float* __restrict__ bias,
    const float* __restrict__ R,
    float* __restrict__ Cf, ushort_t* __restrict__ Cb, int ldc,
    int K)
{
  __shared__ ushort_t As[64*AST];
  __shared__ ushort_t Bs[64*AST];
  int tid = threadIdx.x;
  int w = tid >> 6, lane = tid & 63, quad = lane >> 4, n16 = lane & 15;
  int wm = w >> 1, wn = w & 1;
  int bm = blockIdx.y * 64, bn = blockIdx.x * 64;
  int sr = tid >> 2, sc = (tid & 3) << 4;   // 64 rows x 4 threads x 16 shorts
  const ushort_t* Ag = A  + (size_t)(bm + sr)*lda + sc;
  const ushort_t* Bg = Bt + (size_t)(bn + sr)*ldb + sc;

  f32x4 acc00 = {0.f,0.f,0.f,0.f}, acc01 = acc00, acc10 = acc00, acc11 = acc00;

  float4 av0 = *(const float4*)(Ag);
  float4 av1 = *(const float4*)(Ag + 8);
  float4 bv0 = *(const float4*)(Bg);
  float4 bv1 = *(const float4*)(Bg + 8);
  for (int k0 = 0; k0 < K; k0 += 64) {
    __syncthreads();
    *(float4*)(As + sr*AST + sc)     = av0;
    *(float4*)(As + sr*AST + sc + 8) = av1;
    *(float4*)(Bs + sr*AST + sc)     = bv0;
    *(float4*)(Bs + sr*AST + sc + 8) = bv1;
    __syncthreads();
    if (k0 + 64 < K) {
      av0 = *(const float4*)(Ag + k0 + 64);
      av1 = *(const float4*)(Ag + k0 + 72);
      bv0 = *(const float4*)(Bg + k0 + 64);
      bv1 = *(const float4*)(Bg + k0 + 72);
    }
#pragma unroll
    for (int kk = 0; kk < 64; kk += 32) {
      bf16x8 fa0 = *(const bf16x8*)(As + (wm*32 +      n16)*AST + kk + quad*8);
      bf16x8 fa1 = *(const bf16x8*)(As + (wm*32 + 16 + n16)*AST + kk + quad*8);
      bf16x8 fb0 = *(const bf16x8*)(Bs + (wn*32 +      n16)*AST + kk + quad*8);
      bf16x8 fb1 = *(const bf16x8*)(Bs + (wn*32 + 16 + n16)*AST + kk + quad*8);
      acc00 = __builtin_amdgcn_mfma_f32_16x16x32_bf16(fa0, fb0, acc00, 0,0,0);
      acc01 = __builtin_amdgcn_mfma_f32_16x16x32_bf16(fa0, fb1, acc01, 0,0,0);
      acc10 = __builtin_amdgcn_mfma_f32_16x16x32_bf16(fa1, fb0, acc10, 0,0,0);
      acc11 = __builtin_amdgcn_mfma_f32_16x16x32_bf16(fa1, fb1, acc11, 0,0,0);
    }
  }

  f32x4 accs[2][2] = {{acc00, acc01},{acc10, acc11}};
#pragma unroll
  for (int s = 0; s < 2; ++s)
#pragma unroll
    for (int t = 0; t < 2; ++t) {
      int c = bn + wn*32 + t*16 + n16;
      float bb = bias ? bias[c] : 0.f;
#pragma unroll
      for (int i = 0; i < 4; ++i) {
        int r = bm + wm*32 + s*16 + quad*4 + i;
        float v = accs[s][t][i] + bb;
        if (R)  v += R[(size_t)r*ldc + c];
        if (Cf) Cf[(size_t)r*ldc + c] = v;
        if (Cb) Cb[(size_t)r*ldc + c] = f2bf(v);
      }
    }
}

// ---------------- bf16 MFMA GEMM (TN), 128x64 tile — for N>=960 -------------
#define AS_STRIDE 40
__global__ __launch_bounds__(256) void mgemm128(
    const ushort_t* __restrict__ A, int lda,
    const ushort_t* __restrict__ Bt, int ldb,
    ushort_t* __restrict__ Cb, int ldc, int K)
{
  __shared__ ushort_t As[128*AS_STRIDE];   // 10 KB
  __shared__ ushort_t Bs[64*AS_STRIDE];    // 5 KB
  int tid = threadIdx.x;
  int w = tid >> 6, lane = tid & 63, quad = lane >> 4, n16 = lane & 15;
  int wm = w >> 1, wn = w & 1;
  int bm = blockIdx.y * 128, bn = blockIdx.x * 64;
  int ar = tid >> 1, ac = (tid & 1) << 4;
  int br = tid >> 2, bc = (tid & 3) << 3;
  const ushort_t* Ag = A  + (size_t)(bm + ar)*lda + ac;
  const ushort_t* Bg = Bt + (size_t)(bn + br)*ldb + bc;

  f32x4 acc[4][2];
#pragma unroll
  for (int s = 0; s < 4; ++s)
#pragma unroll
    for (int t = 0; t < 2; ++t) acc[s][t] = f32x4{0.f,0.f,0.f,0.f};

  float4 av0 = *(const float4*)(Ag);
  float4 av1 = *(const float4*)(Ag + 8);
  float4 bv  = *(const float4*)(Bg);
  for (int k0 = 0; k0 < K; k0 += 32) {
    __syncthreads();
    *(float4*)(As + ar*AS_STRIDE + ac)     = av0;
    *(float4*)(As + ar*AS_STRIDE + ac + 8) = av1;
    *(float4*)(Bs + br*AS_STRIDE + bc)     = bv;
    __syncthreads();
    if (k0 + 32 < K) {
      av0 = *(const float4*)(Ag + k0 + 32);
      av1 = *(const float4*)(Ag + k0 + 40);
      bv  = *(const float4*)(Bg + k0 + 32);
    }
    bf16x8 fa[4], fb[2];
#pragma unroll
    for (int s = 0; s < 4; ++s)
      fa[s] = *(const bf16x8*)(As + (wm*64 + s*16 + n16)*AS_STRIDE + quad*8);
#pragma unroll
    for (int t = 0; t < 2; ++t)
      fb[t] = *(const bf16x8*)(Bs + (wn*32 + t*16 + n16)*AS_STRIDE + quad*8);
#pragma unroll
    for (int s = 0; s < 4; ++s)
#pragma unroll
      for (int t = 0; t < 2; ++t)
        acc[s][t] = __builtin_amdgcn_mfma_f32_16x16x32_bf16(fa[s], fb[t], acc[s][t], 0,0,0);
  }

#pragma unroll
  for (int s = 0; s < 4; ++s)
#pragma unroll
    for (int t = 0; t < 2; ++t) {
      int c = bn + wn*32 + t*16 + n16;
#pragma unroll
      for (int i = 0; i < 4; ++i) {
        int r = bm + wm*64 + s*16 + quad*4 + i;
        Cb[(size_t)r*ldc + c] = f2bf(acc[s][t][i]);
      }
    }
}

// -------- ff1 GEMM 128x64 + fused GEGLU: gegb = x * gelu(gate) --------------
__global__ __launch_bounds__(256) void ff1_geglu(
    const ushort_t* __restrict__ A, const ushort_t* __restrict__ Bt,
    const float* __restrict__ bias, ushort_t* __restrict__ Og)
{
  __shared__ ushort_t As[128*AS_STRIDE];
  __shared__ ushort_t Bxs[64*AS_STRIDE];
  __shared__ ushort_t Bgs[64*AS_STRIDE];
  int tid = threadIdx.x;
  int w = tid >> 6, lane = tid & 63, quad = lane >> 4, n16 = lane & 15;
  int wm = w >> 1, wn = w & 1;
  int bm = blockIdx.y * 128, bn = blockIdx.x * 64;
  int ar = tid >> 1, ac = (tid & 1) << 4;
  int br = tid >> 2, bc = (tid & 3) << 3;
  const ushort_t* Ag  = A  + (size_t)(bm + ar)*DIM + ac;
  const ushort_t* Bxg = Bt + (size_t)(bn + br)*DIM + bc;
  const ushort_t* Bgg = Bt + (size_t)(bn + FFD + br)*DIM + bc;

  f32x4 ax[4][2], ag[4][2];
#pragma unroll
  for (int s = 0; s < 4; ++s)
#pragma unroll
    for (int t = 0; t < 2; ++t) { ax[s][t] = f32x4{0.f,0.f,0.f,0.f}; ag[s][t] = ax[s][t]; }

  float4 av0 = *(const float4*)(Ag);
  float4 av1 = *(const float4*)(Ag + 8);
  float4 bxv = *(const float4*)(Bxg);
  float4 bgv = *(const float4*)(Bgg);
  for (int k0 = 0; k0 < DIM; k0 += 32) {
    __syncthreads();
    *(float4*)(As  + ar*AS_STRIDE + ac)     = av0;
    *(float4*)(As  + ar*AS_STRIDE + ac + 8) = av1;
    *(float4*)(Bxs + br*AS_STRIDE + bc)     = bxv;
    *(float4*)(Bgs + br*AS_STRIDE + bc)     = bgv;
    __syncthreads();
    if (k0 + 32 < DIM) {
      av0 = *(const float4*)(Ag  + k0 + 32);
      av1 = *(const float4*)(Ag  + k0 + 40);
      bxv = *(const float4*)(Bxg + k0 + 32);
      bgv = *(const float4*)(Bgg + k0 + 32);
    }
    bf16x8 fa[4], fx[2], fg[2];
#pragma unroll
    for (int s = 0; s < 4; ++s)
      fa[s] = *(const bf16x8*)(As + (wm*64 + s*16 + n16)*AS_STRIDE + quad*8);
#pragma unroll
    for (int t = 0; t < 2; ++t) {
      fx[t] = *(const bf16x8*)(Bxs + (wn*32 + t*16 + n16)*AS_STRIDE + quad*8);
      fg[t] = *(const bf16x8*)(Bgs + (wn*32 + t*16 + n16)*AS_STRIDE + quad*8);
    }
#pragma unroll
    for (int s = 0; s < 4; ++s)
#pragma unroll
      for (int t = 0; t < 2; ++t) {
        ax[s][t] = __builtin_amdgcn_mfma_f32_16x16x32_bf16(fa[s], fx[t], ax[s][t], 0,0,0);
        ag[s][t] = __builtin_amdgcn_mfma_f32_16x16x32_bf16(fa[s], fg[t], ag[s][t], 0,0,0);
      }
  }

  const float kk = 0.7071067811865476f;
#pragma unroll
  for (int s = 0; s < 4; ++s)
#pragma unroll
    for (int t = 0; t < 2; ++t) {
      int c = bn + wn*32 + t*16 + n16;
      float bx = bias[c], bg = bias[c + FFD];
#pragma unroll
      for (int i = 0; i < 4; ++i) {
        int r = bm + wm*64 + s*16 + quad*4 + i;
        float xx = ax[s][t][i] + bx;
        float gg = ag[s][t][i] + bg;
        Og[(size_t)r*FFD + c] = f2bf(xx * 0.5f * gg * (1.f + erff(gg * kk)));
      }
    }
}

// ---------------- MFMA flash attention: 32 q-rows/wave, fixed-max -----------
// R11 configuration exactly — best measured (62 us): 4-wave 256-thread
// blocks at launch_bounds(256,2) (VGPR 84, no spill; R12/R13 showed 1-wave
// blocks pack WORSE and tighter bounds spill). Flat-1024 grid + XCD swizzle
// (R10: FETCH 31->6.7 MB). bf16 partials (R11: WRITE halved).
#define PS_STRIDE 40

__global__ __launch_bounds__(256, 2) void attn_mfma(
    const ushort_t* __restrict__ qkv, const ushort_t* __restrict__ Kp,
    const ushort_t* __restrict__ Vt,
    float* __restrict__ Pl, ushort_t* __restrict__ Pacc)
{
  __shared__ ushort_t Ps[4*32*PS_STRIDE];
  int tid  = threadIdx.x;
  int w    = tid >> 6;
  int lane = tid & 63;
  int quad = lane >> 4;
  int n16  = lane & 15;
  ushort_t* Psw = Ps + w*32*PS_STRIDE;

  int blk  = blockIdx.x;
  int bh   = (blk & 7) | (((blk >> 3) & 1) << 3);
  int rest = blk >> 4;            // 0..63
  int qt   = rest & 15;
  int ks   = rest >> 4;           // 0..3
  int b = bh >> 3, h = bh & 7;

  const ushort_t* qrowa = qkv + (size_t)(b*LQ + qt*128 + w*32 + n16)*960 + h*HD;
  const ushort_t* qrowb = qrowa + 16*960;
  bf16x8 qf0a = *(const bf16x8*)(qrowa + quad*8);
  bf16x8 qf1a = *(const bf16x8*)(qrowa + 32);  // quads>0: garbage x Kp-pad(0) = 0
  bf16x8 qf0b = *(const bf16x8*)(qrowb + quad*8);
  bf16x8 qf1b = *(const bf16x8*)(qrowb + 32);

  const ushort_t* Kh = Kp + (size_t)bh*2048*64;
  const ushort_t* Vh = Vt + (size_t)bh*48*2048;
  int k0 = ks*KCHUNK;
  int koff0 = n16*64 + quad*8;
  int koff1 = (16+n16)*64 + quad*8;
  int voff = quad*8;

  f32x4 o0a = {0.f,0.f,0.f,0.f}, o1a = o0a, o2a = o0a;
  f32x4 o0b = o0a, o1b = o0a, o2b = o0a;
  f32x4 la0a = o0a, la1a = o0a, la0b = o0a, la1b = o0a;

#define LOAD_TILE(T0, K00,K01,K10,K11,V0,V1,V2) { \
  const ushort_t* Kt_ = Kh + (size_t)(k0 + (T0))*64; \
  const ushort_t* Vt_ = Vh + k0 + (T0); \
  K00 = *(const bf16x8*)(Kt_ + koff0); \
  K01 = *(const bf16x8*)(Kt_ + koff0 + 32); \
  K10 = *(const bf16x8*)(Kt_ + koff1); \
  K11 = *(const bf16x8*)(Kt_ + koff1 + 32); \
  V0 = *(const bf16x8*)(Vt_ + (size_t)(n16)*2048 + voff); \
  V1 = *(const bf16x8*)(Vt_ + (size_t)(16+n16)*2048 + voff); \
  V2 = *(const bf16x8*)(Vt_ + (size_t)(32+n16)*2048 + voff); }

#define COMPUTE(K00,K01,K10,K11,V0,V1,V2) { \
  f32x4 s0a = {-8.f,-8.f,-8.f,-8.f}; f32x4 s1a = s0a, s0b = s0a, s1b = s0a; \
  s0a = __builtin_amdgcn_mfma_f32_16x16x32_bf16(qf0a, K00, s0a, 0,0,0); \
  s1a = __builtin_amdgcn_mfma_f32_16x16x32_bf16(qf0a, K10, s1a, 0,0,0); \
  s0b = __builtin_amdgcn_mfma_f32_16x16x32_bf16(qf0b, K00, s0b, 0,0,0); \
  s1b = __builtin_amdgcn_mfma_f32_16x16x32_bf16(qf0b, K10, s1b, 0,0,0); \
  s0a = __builtin_amdgcn_mfma_f32_16x16x32_bf16(qf1a, K01, s0a, 0,0,0); \
  s1a = __builtin_amdgcn_mfma_f32_16x16x32_bf16(qf1a, K11, s1a, 0,0,0); \
  s0b = __builtin_amdgcn_mfma_f32_16x16x32_bf16(qf1b, K01, s0b, 0,0,0); \
  s1b = __builtin_amdgcn_mfma_f32_16x16x32_bf16(qf1b, K11, s1b, 0,0,0); \
  f32x4 p0a, p1a, p0b, p1b; \
  _Pragma("unroll") \
  for (int r = 0; r < 4; ++r) { \
    p0a[r] = EXP2F(s0a[r]); p1a[r] = EXP2F(s1a[r]); \
    p0b[r] = EXP2F(s0b[r]); p1b[r] = EXP2F(s1b[r]); \
  } \
  la0a += p0a; la1a += p1a; la0b += p0b; la1b += p1b; \
  _Pragma("unroll") \
  for (int r = 0; r < 4; ++r) { \
    int row = quad*4 + r; \
    Psw[row*PS_STRIDE + n16]           = (ushort_t)(__float_as_uint(p0a[r]) >> 16); \
    Psw[row*PS_STRIDE + 16 + n16]      = (ushort_t)(__float_as_uint(p1a[r]) >> 16); \
    Psw[(16+row)*PS_STRIDE + n16]      = (ushort_t)(__float_as_uint(p0b[r]) >> 16); \
    Psw[(16+row)*PS_STRIDE + 16 + n16] = (ushort_t)(__float_as_uint(p1b[r]) >> 16); \
  } \
  bf16x8 paa = *(const bf16x8*)(Psw + n16*PS_STRIDE + quad*8); \
  bf16x8 pab = *(const bf16x8*)(Psw + (16+n16)*PS_STRIDE + quad*8); \
  o0a = __builtin_amdgcn_mfma_f32_16x16x32_bf16(paa, V0, o0a, 0,0,0); \
  o0b = __builtin_amdgcn_mfma_f32_16x16x32_bf16(pab, V0, o0b, 0,0,0); \
  o1a = __builtin_amdgcn_mfma_f32_16x16x32_bf16(paa, V1, o1a, 0,0,0); \
  o1b = __builtin_amdgcn_mfma_f32_16x16x32_bf16(pab, V1, o1b, 0,0,0); \
  o2a = __builtin_amdgcn_mfma_f32_16x16x32_bf16(paa, V2, o2a, 0,0,0); \
  o2b = __builtin_amdgcn_mfma_f32_16x16x32_bf16(pab, V2, o2b, 0,0,0); }

  bf16x8 ka0,ka1,ka2,ka3,va0,va1,va2;
  bf16x8 kb0,kb1,kb2,kb3,vb0,vb1,vb2;
  LOAD_TILE(0, ka0,ka1,ka2,ka3,va0,va1,va2);
  for (int t0 = 0; t0 < KCHUNK; t0 += 2*KT) {
    LOAD_TILE(t0 + KT, kb0,kb1,kb2,kb3,vb0,vb1,vb2);
    COMPUTE(ka0,ka1,ka2,ka3,va0,va1,va2);
    if (t0 + 2*KT < KCHUNK) {
      LOAD_TILE(t0 + 2*KT, ka0,ka1,ka2,ka3,va0,va1,va2);
    }
    COMPUTE(kb0,kb1,kb2,kb3,vb0,vb1,vb2);
  }
#undef LOAD_TILE
#undef COMPUTE

  float lra[4], lrb[4];
#pragma unroll
  for (int r = 0; r < 4; ++r) { lra[r] = la0a[r] + la1a[r]; lrb[r] = la0b[r] + la1b[r]; }
#pragma unroll
  for (int off = 1; off < 16; off <<= 1)
#pragma unroll
    for (int r = 0; r < 4; ++r) {
      lra[r] += __shfl_xor(lra[r], off, 64);
      lrb[r] += __shfl_xor(lrb[r], off, 64);
    }

  int gqa = bh*LQ + qt*128 + w*32 + quad*4;
  size_t base = (size_t)ks*NQROWS;
#pragma unroll
  for (int r = 0; r < 4; ++r) {
    size_t gq = base + gqa + r;
    ushort_t* pw = Pacc + gq*40;
    pw[n16]      = f2bf(o0a[r]);
    pw[16 + n16] = f2bf(o1a[r]);
    if (n16 < 8) pw[32 + n16] = f2bf(o2a[r]);
    if (n16 == 0) Pl[gq] = lra[r];
    size_t gq2 = gq + 16;
    ushort_t* pw2 = Pacc + gq2*40;
    pw2[n16]      = f2bf(o0b[r]);
    pw2[16 + n16] = f2bf(o1b[r]);
    if (n16 < 8) pw2[32 + n16] = f2bf(o2b[r]);
    if (n16 == 0) Pl[gq2] = lrb[r];
  }
}

// Merge KSPLIT bf16 partials per q-row -> bf16 O [4096][320]
__global__ __launch_bounds__(256) void attn_merge(
    const float* __restrict__ Pl, const ushort_t* __restrict__ Pacc,
    ushort_t* __restrict__ O)
{
  int idx = blockIdx.x*256 + threadIdx.x;   // 0..32767
  int bh = idx >> 11, qi = idx & (LQ-1);
  int b = bh >> 3, h = bh & 7;
  float L = 0.f;
#pragma unroll
  for (int k = 0; k < KSPLIT; ++k) L += Pl[(size_t)k*NQROWS + idx];
  float inv = 1.0f / L;
  ushort_t* orow = O + (size_t)(b*LQ + qi)*DIM + h*HD;
#pragma unroll
  for (int u = 0; u < 5; ++u) {           // 5 chunks of 8 cols
    float acc[8] = {0,0,0,0,0,0,0,0};
#pragma unroll
    for (int k = 0; k < KSPLIT; ++k) {
      const ushort_t* pr = Pacc + ((size_t)k*NQROWS + idx)*40 + u*8;
      ushort_t vbuf[8];
      *(uint4*)vbuf = *(const uint4*)pr;
#pragma unroll
      for (int j = 0; j < 8; ++j) acc[j] += bf2f(vbuf[j]);
    }
    ushort_t ob[8];
#pragma unroll
    for (int j = 0; j < 8; ++j) ob[j] = f2bf(acc[j]*inv);
    *(uint4*)(orow + u*8) = *(uint4*)ob;
  }
}

extern "C" void kernel_launch(void* const* d_in, const int* in_sizes, int n_in,
                              void* d_out, int out_size, void* d_ws, size_t ws_size,
                              hipStream_t stream) {
  const float* hidden = (const float*)d_in[0];
  // d_in[1] encoder_hidden_states: UNUSED (softmax rows sum to 1 -> cross == vH)
  const float* ln1_g = (const float*)d_in[2];
  const float* ln1_b = (const float*)d_in[3];
  const float* wq1   = (const float*)d_in[4];
  const float* wk1   = (const float*)d_in[5];
  const float* wv1   = (const float*)d_in[6];
  const float* wo1   = (const float*)d_in[7];
  const float* bo1   = (const float*)d_in[8];
  const float* ln2_g = (const float*)d_in[9];
  const float* ln2_b = (const float*)d_in[10];
  // d_in[11] wq2, d_in[12] wk2: UNUSED
  const float* wvh   = (const float*)d_in[13];
  const float* wo2   = (const float*)d_in[14];
  const float* bo2   = (const float*)d_in[15];
  const float* ln3_g = (const float*)d_in[16];
  const float* ln3_b = (const float*)d_in[17];
  const float* wff1  = (const float*)d_in[18];
  const float* bff1  = (const float*)d_in[19];
  const float* wff2  = (const float*)d_in[20];
  const float* bff2  = (const float*)d_in[21];
  float* out = (float*)d_out;

  // workspace: bf16 region (shorts) then fp32 region
  ushort_t* wsu = (ushort_t*)d_ws;
  ushort_t* wbf   = wsu;                          // WBF_TOTAL shorts
  ushort_t* lnb   = wbf + WBF_TOTAL;              // 4096*320
  ushort_t* qkvb  = lnb + (size_t)MROWS*DIM;      // 4096*960
  ushort_t* attnb = qkvb + (size_t)MROWS*3*DIM;   // 4096*320
  ushort_t* gegb  = attnb + (size_t)MROWS*DIM;    // 4096*1280
  ushort_t* wct   = gegb + (size_t)MROWS*FFD;     // 320*320
  ushort_t* vtb   = wct + 320*320;                // 16*48*2048
  ushort_t* kpb   = vtb + (size_t)16*48*2048;     // 16*2048*64
  ushort_t* Pacc  = kpb + (size_t)16*2048*64;     // KSPLIT*32768*40 bf16
  float* fws = (float*)(Pacc + (size_t)KSPLIT*NQROWS*40 + 64);
  float* h1   = fws;                              // 4096*320
  float* h2   = h1 + (size_t)MROWS*DIM;
  float* Pl   = h2 + (size_t)MROWS*DIM;           // KSPLIT*32768

  dim3 t256(256);
  dim3 gconv(800, 8);
  dim3 gqkv(15, 32);     // N=960, 128-row tiles -> 480 blocks
  dim3 g320(5, 64);      // N=320, 64-row tiles -> 320 blocks
  dim3 gwc(5, 5);        // 320x320
  dim3 gffg(20, 32);     // ff1+geglu, 128-row tiles -> 640 blocks
  dim3 gvt(32, 16);
  dim3 gattn(16*16*KSPLIT);   // flat 1024 4-wave blocks, XCD swizzle inside

  convw_kernel<<<gconv, t256, 0, stream>>>(wq1, wk1, wv1, wo1, wo2, wff1, wff2, wvh, wbf);
  // Wc^T = wo2^T @ wvh^T (tiny)
  mgemm<<<gwc, t256, 0, stream>>>(wbf + OFF_WO2T, DIM, wbf + OFF_WVHB, DIM,
                                  nullptr, nullptr, nullptr, wct, DIM, DIM);

  // Stage 1: self-attention
  ln_kernel<<<MROWS/4, t256, 0, stream>>>(hidden, ln1_g, ln1_b, lnb);
  mgemm128<<<gqkv, t256, 0, stream>>>(lnb, DIM, wbf + OFF_WQKVT, DIM,
                                      qkvb, 3*DIM, DIM);
  vt_kernel<<<gvt, t256, 0, stream>>>(qkvb, vtb, kpb);
  attn_mfma<<<gattn, t256, 0, stream>>>(qkvb, kpb, vtb, Pl, Pacc);
  attn_merge<<<NQROWS/256, t256, 0, stream>>>(Pl, Pacc, attnb);
  mgemm<<<g320, t256, 0, stream>>>(attnb, DIM, wbf + OFF_WO1T, DIM, bo1, hidden,
                                   h1, nullptr, DIM, DIM);

  // Stage 2: cross == ln2(h1) @ (wvh@wo2) + bo2 + h1   (softmax sums to 1)
  ln_kernel<<<MROWS/4, t256, 0, stream>>>(h1, ln2_g, ln2_b, lnb);
  mgemm<<<g320, t256, 0, stream>>>(lnb, DIM, wct, DIM, bo2, h1,
                                   h2, nullptr, DIM, DIM);

  // Stage 3: GEGLU FF
  ln_kernel<<<MROWS/4, t256, 0, stream>>>(h2, ln3_g, ln3_b, lnb);
  ff1_geglu<<<gffg, t256, 0, stream>>>(lnb, wbf + OFF_WFF1T, bff1, gegb);
  mgemm<<<g320, t256, 0, stream>>>(gegb, FFD, wbf + OFF_WFF2T, FFD, bff2, h2,
                                   out, nullptr, DIM, FFD);
}

// Round 15
// 248.805 us; speedup vs baseline: 1.1049x; 1.0122x over previous
//
#include <hip/hip_runtime.h>
#include <math.h>

// Problem constants
#define DIM   320
#define HD    40
#define NH    8
#define LQ    2048
#define BATCH 2
#define MROWS 4096
#define FFD   1280
#define FF2   2560

#define KSPLIT 4
#define KCHUNK (LQ/KSPLIT) // 512
#define KT     32
#define NQROWS (BATCH*NH*LQ)  // 32768

#define LSCALE (0.15811388300841897f * 1.4426950408889634f)

typedef unsigned short ushort_t;
using bf16x8 = __attribute__((ext_vector_type(8))) short;
using f32x4  = __attribute__((ext_vector_type(4))) float;

static __device__ inline ushort_t f2bf(float f) {
  union { float f; unsigned u; } x{f};
  unsigned r = x.u + 0x7FFFu + ((x.u >> 16) & 1u);
  return (ushort_t)(r >> 16);
}
static __device__ inline float bf2f(ushort_t h) {
  union { unsigned u; float f; } x; x.u = ((unsigned)h) << 16; return x.f;
}

// ---------------- LayerNorm: one wave per row of 320, bf16 out ---------------
__global__ __launch_bounds__(256) void ln_kernel(
    const float* __restrict__ X, const float* __restrict__ g,
    const float* __restrict__ bta, ushort_t* __restrict__ Y)
{
  int row  = blockIdx.x * 4 + (threadIdx.x >> 6);
  int lane = threadIdx.x & 63;
  const float* x = X + (size_t)row * DIM;
  float v[5];
  float s = 0.f;
#pragma unroll
  for (int i = 0; i < 5; ++i) { v[i] = x[lane + 64*i]; s += v[i]; }
#pragma unroll
  for (int off = 32; off >= 1; off >>= 1) s += __shfl_xor(s, off, 64);
  float mean = s * (1.0f/DIM);
  float sq = 0.f;
#pragma unroll
  for (int i = 0; i < 5; ++i) { float d = v[i] - mean; sq += d*d; }
#pragma unroll
  for (int off = 32; off >= 1; off >>= 1) sq += __shfl_xor(sq, off, 64);
  float rstd = rsqrtf(sq*(1.0f/DIM) + 1e-5f);
  ushort_t* y = Y + (size_t)row * DIM;
#pragma unroll
  for (int i = 0; i < 5; ++i) {
    int c = lane + 64*i;
    y[c] = f2bf((v[i]-mean)*rstd*g[c] + bta[c]);
  }
}

// ---------------- Weight convert/transpose to bf16, k-fastest ---------------
#define OFF_WQKVT 0
#define OFF_WO1T  (960*320)
#define OFF_WO2T  (OFF_WO1T + 320*320)
#define OFF_WFF1T (OFF_WO2T + 320*320)
#define OFF_WFF2T (OFF_WFF1T + 320*2560)
#define OFF_WVHB  (OFF_WFF2T + 1280*320)
#define WBF_TOTAL (OFF_WVHB + 320*320)

__global__ __launch_bounds__(256) void convw_kernel(
    const float* __restrict__ wq1, const float* __restrict__ wk1,
    const float* __restrict__ wv1, const float* __restrict__ wo1,
    const float* __restrict__ wo2, const float* __restrict__ wff1,
    const float* __restrict__ wff2, const float* __restrict__ wvh,
    ushort_t* __restrict__ dst)
{
  int e = blockIdx.y;
  const float* src; int K, N; size_t doff; int tr = 1; float scale = 1.f;
  switch (e) {
    case 0: src=wq1;  K=320;  N=320;  doff=OFF_WQKVT; scale=LSCALE; break;
    case 1: src=wk1;  K=320;  N=320;  doff=OFF_WQKVT + 320*320;  break;
    case 2: src=wv1;  K=320;  N=320;  doff=OFF_WQKVT + 2*320*320;break;
    case 3: src=wo1;  K=320;  N=320;  doff=OFF_WO1T;             break;
    case 4: src=wo2;  K=320;  N=320;  doff=OFF_WO2T;             break;
    case 5: src=wff1; K=320;  N=2560; doff=OFF_WFF1T;            break;
    case 6: src=wff2; K=1280; N=320;  doff=OFF_WFF2T;            break;
    default: src=wvh; K=320;  N=320;  doff=OFF_WVHB; tr=0;       break;
  }
  int ntN = N/32;
  int nt_total = (K/32)*ntN;
  int t = blockIdx.x;
  if (t >= nt_total) return;
  int kt = t / ntN, nt = t - kt*ntN;
  __shared__ float tile[32][33];
  int tx = threadIdx.x & 31, ty = threadIdx.x >> 5;
  ushort_t* d = dst + doff;
#pragma unroll
  for (int i = 0; i < 4; ++i) {
    int r = ty + 8*i;
    tile[r][tx] = src[(size_t)(kt*32+r)*N + nt*32+tx] * scale;
  }
  __syncthreads();
  if (tr) {
#pragma unroll
    for (int i = 0; i < 4; ++i) {
      int r = ty + 8*i;
      d[(size_t)(nt*32+r)*K + kt*32+tx] = f2bf(tile[tx][r]);
    }
  } else {
#pragma unroll
    for (int i = 0; i < 4; ++i) {
      int r = ty + 8*i;
      d[(size_t)(kt*32+r)*N + nt*32+tx] = f2bf(tile[r][tx]);
    }
  }
}

// ---- K/V repack: qkv [4096][960] -> Kp[16][2048][64] (d-pad 0) and
//      Vt[16][48][2048] (transposed, d-pad rows 0). Grid (32, 16).
__global__ __launch_bounds__(256) void vt_kernel(
    const ushort_t* __restrict__ qkv, ushort_t* __restrict__ Vt,
    ushort_t* __restrict__ Kp)
{
  int bh = blockIdx.y;
  int kt = blockIdx.x;
  int b = bh >> 3, h = bh & 7;
  int tid = threadIdx.x;
  __shared__ ushort_t tile[64*42];

  const ushort_t* ksrc = qkv + (size_t)(b*LQ + kt*64)*960 + DIM + h*HD;
  ushort_t* kdst = Kp + ((size_t)bh*2048 + (size_t)kt*64)*64;
#pragma unroll
  for (int i = 0; i < 2; ++i) {
    int f = i*256 + tid;
    if (f < 320) {
      int r = f/5, s = f - 5*r;
      *(uint4*)(kdst + r*64 + s*8) = *(const uint4*)(ksrc + (size_t)r*960 + s*8);
    }
  }
  if (tid < 192) {
    int r = tid/3, s = tid - 3*r;
    uint4 z = {0,0,0,0};
    *(uint4*)(kdst + r*64 + 40 + s*8) = z;
  }

  const ushort_t* vsrc = qkv + (size_t)(b*LQ + kt*64)*960 + 2*DIM + h*HD;
#pragma unroll
  for (int i = 0; i < 5; ++i) {
    int f = i*256 + tid;
    int r = f/20, c2 = f - r*20;
    *(unsigned*)(tile + r*42 + c2*2) = *(const unsigned*)(vsrc + (size_t)r*960 + c2*2);
  }
  __syncthreads();
  ushort_t* dstp = Vt + (size_t)bh*48*2048 + kt*64;
#pragma unroll
  for (int i = 0; i < 6; ++i) {
    int f = i*256 + tid;
    int dd = f >> 5, kk = f & 31;
    unsigned val = 0;
    if (dd < 40) {
      unsigned lo = tile[(kk*2)*42 + dd];
      unsigned hi = tile[(kk*2+1)*42 + dd];
      val = lo | (hi << 16);
    }
    *(unsigned*)(dstp + (size_t)dd*2048 + kk*2) = val;
  }
}

// ---------------- bf16 MFMA GEMM (TN), 64x64 tile, BK=64, reg prefetch ------
// BK=64: 5 K-iterations instead of 10; 8 MFMA per wave between barriers
// (R13: rest -15 us vs BK=32).
#define AST 72   // 64 k + 8 pad shorts: 36-dword rows -> 2-way bank (free)
__global__ __launch_bounds__(256) void mgemm(
    const ushort_t* __restrict__ A, int lda,
    const ushort_t* __restrict__ Bt, int ldb,
    const float* __restrict__ bias,
    const float* __restrict__ R,
    float* __restrict__ Cf, ushort_t* __restrict__ Cb, int ldc,
    int K)
{
  __shared__ ushort_t As[64*AST];
  __shared__ ushort_t Bs[64*AST];
  int tid = threadIdx.x;
  int w = tid >> 6, lane = tid & 63, quad = lane >> 4, n16 = lane & 15;
  int wm = w >> 1, wn = w & 1;
  int bm = blockIdx.y * 64, bn = blockIdx.x * 64;
  int sr = tid >> 2, sc = (tid & 3) << 4;   // 64 rows x 4 threads x 16 shorts
  const ushort_t* Ag = A  + (size_t)(bm + sr)*lda + sc;
  const ushort_t* Bg = Bt + (size_t)(bn + sr)*ldb + sc;

  f32x4 acc00 = {0.f,0.f,0.f,0.f}, acc01 = acc00, acc10 = acc00, acc11 = acc00;

  float4 av0 = *(const float4*)(Ag);
  float4 av1 = *(const float4*)(Ag + 8);
  float4 bv0 = *(const float4*)(Bg);
  float4 bv1 = *(const float4*)(Bg + 8);
  for (int k0 = 0; k0 < K; k0 += 64) {
    __syncthreads();
    *(float4*)(As + sr*AST + sc)     = av0;
    *(float4*)(As + sr*AST + sc + 8) = av1;
    *(float4*)(Bs + sr*AST + sc)     = bv0;
    *(float4*)(Bs + sr*AST + sc + 8) = bv1;
    __syncthreads();
    if (k0 + 64 < K) {
      av0 = *(const float4*)(Ag + k0 + 64);
      av1 = *(const float4*)(Ag + k0 + 72);
      bv0 = *(const float4*)(Bg + k0 + 64);
      bv1 = *(const float4*)(Bg + k0 + 72);
    }
#pragma unroll
    for (int kk = 0; kk < 64; kk += 32) {
      bf16x8 fa0 = *(const bf16x8*)(As + (wm*32 +      n16)*AST + kk + quad*8);
      bf16x8 fa1 = *(const bf16x8*)(As + (wm*32 + 16 + n16)*AST + kk + quad*8);
      bf16x8 fb0 = *(const bf16x8*)(Bs + (wn*32 +      n16)*AST + kk + quad*8);
      bf16x8 fb1 = *(const bf16x8*)(Bs + (wn*32 + 16 + n16)*AST + kk + quad*8);
      acc00 = __builtin_amdgcn_mfma_f32_16x16x32_bf16(fa0, fb0, acc00, 0,0,0);
      acc01 = __builtin_amdgcn_mfma_f32_16x16x32_bf16(fa0, fb1, acc01, 0,0,0);
      acc10 = __builtin_amdgcn_mfma_f32_16x16x32_bf16(fa1, fb0, acc10, 0,0,0);
      acc11 = __builtin_amdgcn_mfma_f32_16x16x32_bf16(fa1, fb1, acc11, 0,0,0);
    }
  }

  f32x4 accs[2][2] = {{acc00, acc01},{acc10, acc11}};
#pragma unroll
  for (int s = 0; s < 2; ++s)
#pragma unroll
    for (int t = 0; t < 2; ++t) {
      int c = bn + wn*32 + t*16 + n16;
      float bb = bias ? bias[c] : 0.f;
#pragma unroll
      for (int i = 0; i < 4; ++i) {
        int r = bm + wm*32 + s*16 + quad*4 + i;
        float v = accs[s][t][i] + bb;
        if (R)  v += R[(size_t)r*ldc + c];
        if (Cf) Cf[(size_t)r*ldc + c] = v;
        if (Cb) Cb[(size_t)r*ldc + c] = f2bf(v);
      }
    }
}

// ---------------- bf16 MFMA GEMM (TN), 128x64 tile — for N>=960 -------------
#define AS_STRIDE 40
__global__ __launch_bounds__(256) void mgemm128(
    const ushort_t* __restrict__ A, int lda,
    const ushort_t* __restrict__ Bt, int ldb,
    ushort_t* __restrict__ Cb, int ldc, int K)
{
  __shared__ ushort_t As[128*AS_STRIDE];   // 10 KB
  __shared__ ushort_t Bs[64*AS_STRIDE];    // 5 KB
  int tid = threadIdx.x;
  int w = tid >> 6, lane = tid & 63, quad = lane >> 4, n16 = lane & 15;
  int wm = w >> 1, wn = w & 1;
  int bm = blockIdx.y * 128, bn = blockIdx.x * 64;
  int ar = tid >> 1, ac = (tid & 1) << 4;
  int br = tid >> 2, bc = (tid & 3) << 3;
  const ushort_t* Ag = A  + (size_t)(bm + ar)*lda + ac;
  const ushort_t* Bg = Bt + (size_t)(bn + br)*ldb + bc;

  f32x4 acc[4][2];
#pragma unroll
  for (int s = 0; s < 4; ++s)
#pragma unroll
    for (int t = 0; t < 2; ++t) acc[s][t] = f32x4{0.f,0.f,0.f,0.f};

  float4 av0 = *(const float4*)(Ag);
  float4 av1 = *(const float4*)(Ag + 8);
  float4 bv  = *(const float4*)(Bg);
  for (int k0 = 0; k0 < K; k0 += 32) {
    __syncthreads();
    *(float4*)(As + ar*AS_STRIDE + ac)     = av0;
    *(float4*)(As + ar*AS_STRIDE + ac + 8) = av1;
    *(float4*)(Bs + br*AS_STRIDE + bc)     = bv;
    __syncthreads();
    if (k0 + 32 < K) {
      av0 = *(const float4*)(Ag + k0 + 32);
      av1 = *(const float4*)(Ag + k0 + 40);
      bv  = *(const float4*)(Bg + k0 + 32);
    }
    bf16x8 fa[4], fb[2];
#pragma unroll
    for (int s = 0; s < 4; ++s)
      fa[s] = *(const bf16x8*)(As + (wm*64 + s*16 + n16)*AS_STRIDE + quad*8);
#pragma unroll
    for (int t = 0; t < 2; ++t)
      fb[t] = *(const bf16x8*)(Bs + (wn*32 + t*16 + n16)*AS_STRIDE + quad*8);
#pragma unroll
    for (int s = 0; s < 4; ++s)
#pragma unroll
      for (int t = 0; t < 2; ++t)
        acc[s][t] = __builtin_amdgcn_mfma_f32_16x16x32_bf16(fa[s], fb[t], acc[s][t], 0,0,0);
  }

#pragma unroll
  for (int s = 0; s < 4; ++s)
#pragma unroll
    for (int t = 0; t < 2; ++t) {
      int c = bn + wn*32 + t*16 + n16;
#pragma unroll
      for (int i = 0; i < 4; ++i) {
        int r = bm + wm*64 + s*16 + quad*4 + i;
        Cb[(size_t)r*ldc + c] = f2bf(acc[s][t][i]);
      }
    }
}

// -------- ff1 GEMM 128x64 + fused GEGLU: gegb = x * gelu(gate) --------------
__global__ __launch_bounds__(256) void ff1_geglu(
    const ushort_t* __restrict__ A, const ushort_t* __restrict__ Bt,
    const float* __restrict__ bias, ushort_t* __restrict__ Og)
{
  __shared__ ushort_t As[128*AS_STRIDE];
  __shared__ ushort_t Bxs[64*AS_STRIDE];
  __shared__ ushort_t Bgs[64*AS_STRIDE];
  int tid = threadIdx.x;
  int w = tid >> 6, lane = tid & 63, quad = lane >> 4, n16 = lane & 15;
  int wm = w >> 1, wn = w & 1;
  int bm = blockIdx.y * 128, bn = blockIdx.x * 64;
  int ar = tid >> 1, ac = (tid & 1) << 4;
  int br = tid >> 2, bc = (tid & 3) << 3;
  const ushort_t* Ag  = A  + (size_t)(bm + ar)*DIM + ac;
  const ushort_t* Bxg = Bt + (size_t)(bn + br)*DIM + bc;
  const ushort_t* Bgg = Bt + (size_t)(bn + FFD + br)*DIM + bc;

  f32x4 ax[4][2], ag[4][2];
#pragma unroll
  for (int s = 0; s < 4; ++s)
#pragma unroll
    for (int t = 0; t < 2; ++t) { ax[s][t] = f32x4{0.f,0.f,0.f,0.f}; ag[s][t] = ax[s][t]; }

  float4 av0 = *(const float4*)(Ag);
  float4 av1 = *(const float4*)(Ag + 8);
  float4 bxv = *(const float4*)(Bxg);
  float4 bgv = *(const float4*)(Bgg);
  for (int k0 = 0; k0 < DIM; k0 += 32) {
    __syncthreads();
    *(float4*)(As  + ar*AS_STRIDE + ac)     = av0;
    *(float4*)(As  + ar*AS_STRIDE + ac + 8) = av1;
    *(float4*)(Bxs + br*AS_STRIDE + bc)     = bxv;
    *(float4*)(Bgs + br*AS_STRIDE + bc)     = bgv;
    __syncthreads();
    if (k0 + 32 < DIM) {
      av0 = *(const float4*)(Ag  + k0 + 32);
      av1 = *(const float4*)(Ag  + k0 + 40);
      bxv = *(const float4*)(Bxg + k0 + 32);
      bgv = *(const float4*)(Bgg + k0 + 32);
    }
    bf16x8 fa[4], fx[2], fg[2];
#pragma unroll
    for (int s = 0; s < 4; ++s)
      fa[s] = *(const bf16x8*)(As + (wm*64 + s*16 + n16)*AS_STRIDE + quad*8);
#pragma unroll
    for (int t = 0; t < 2; ++t) {
      fx[t] = *(const bf16x8*)(Bxs + (wn*32 + t*16 + n16)*AS_STRIDE + quad*8);
      fg[t] = *(const bf16x8*)(Bgs + (wn*32 + t*16 + n16)*AS_STRIDE + quad*8);
    }
#pragma unroll
    for (int s = 0; s < 4; ++s)
#pragma unroll
      for (int t = 0; t < 2; ++t) {
        ax[s][t] = __builtin_amdgcn_mfma_f32_16x16x32_bf16(fa[s], fx[t], ax[s][t], 0,0,0);
        ag[s][t] = __builtin_amdgcn_mfma_f32_16x16x32_bf16(fa[s], fg[t], ag[s][t], 0,0,0);
      }
  }

  const float kk = 0.7071067811865476f;
#pragma unroll
  for (int s = 0; s < 4; ++s)
#pragma unroll
    for (int t = 0; t < 2; ++t) {
      int c = bn + wn*32 + t*16 + n16;
      float bx = bias[c], bg = bias[c + FFD];
#pragma unroll
      for (int i = 0; i < 4; ++i) {
        int r = bm + wm*64 + s*16 + quad*4 + i;
        float xx = ax[s][t][i] + bx;
        float gg = ag[s][t][i] + bg;
        Og[(size_t)r*FFD + c] = f2bf(xx * 0.5f * gg * (1.f + erff(gg * kk)));
      }
    }
}

// ---------------- MFMA flash attention: 32 q-rows/wave, fixed-max -----------
// R11 configuration EXACTLY, including ocml exp2f — the R14 A/B showed the
// raw __builtin_amdgcn_exp2f costs +9 us (VGPR 84->80, Occupancy 26->21%:
// the opaque intrinsic pins the dependency chain; ocml exp2f schedules
// freely). 4-wave (256,2) blocks (R12/R13: 1-wave packs worse; tighter
// bounds spill). Flat-1024 grid + XCD swizzle (R10). bf16 partials (R11).
#define PS_STRIDE 40

__global__ __launch_bounds__(256, 2) void attn_mfma(
    const ushort_t* __restrict__ qkv, const ushort_t* __restrict__ Kp,
    const ushort_t* __restrict__ Vt,
    float* __restrict__ Pl, ushort_t* __restrict__ Pacc)
{
  __shared__ ushort_t Ps[4*32*PS_STRIDE];
  int tid  = threadIdx.x;
  int w    = tid >> 6;
  int lane = tid & 63;
  int quad = lane >> 4;
  int n16  = lane & 15;
  ushort_t* Psw = Ps + w*32*PS_STRIDE;

  int blk  = blockIdx.x;
  int bh   = (blk & 7) | (((blk >> 3) & 1) << 3);
  int rest = blk >> 4;            // 0..63
  int qt   = rest & 15;
  int ks   = rest >> 4;           // 0..3
  int b = bh >> 3, h = bh & 7;

  const ushort_t* qrowa = qkv + (size_t)(b*LQ + qt*128 + w*32 + n16)*960 + h*HD;
  const ushort_t* qrowb = qrowa + 16*960;
  bf16x8 qf0a = *(const bf16x8*)(qrowa + quad*8);
  bf16x8 qf1a = *(const bf16x8*)(qrowa + 32);  // quads>0: garbage x Kp-pad(0) = 0
  bf16x8 qf0b = *(const bf16x8*)(qrowb + quad*8);
  bf16x8 qf1b = *(const bf16x8*)(qrowb + 32);

  const ushort_t* Kh = Kp + (size_t)bh*2048*64;
  const ushort_t* Vh = Vt + (size_t)bh*48*2048;
  int k0 = ks*KCHUNK;
  int koff0 = n16*64 + quad*8;
  int koff1 = (16+n16)*64 + quad*8;
  int voff = quad*8;

  f32x4 o0a = {0.f,0.f,0.f,0.f}, o1a = o0a, o2a = o0a;
  f32x4 o0b = o0a, o1b = o0a, o2b = o0a;
  f32x4 la0a = o0a, la1a = o0a, la0b = o0a, la1b = o0a;

#define LOAD_TILE(T0, K00,K01,K10,K11,V0,V1,V2) { \
  const ushort_t* Kt_ = Kh + (size_t)(k0 + (T0))*64; \
  const ushort_t* Vt_ = Vh + k0 + (T0); \
  K00 = *(const bf16x8*)(Kt_ + koff0); \
  K01 = *(const bf16x8*)(Kt_ + koff0 + 32); \
  K10 = *(const bf16x8*)(Kt_ + koff1); \
  K11 = *(const bf16x8*)(Kt_ + koff1 + 32); \
  V0 = *(const bf16x8*)(Vt_ + (size_t)(n16)*2048 + voff); \
  V1 = *(const bf16x8*)(Vt_ + (size_t)(16+n16)*2048 + voff); \
  V2 = *(const bf16x8*)(Vt_ + (size_t)(32+n16)*2048 + voff); }

#define COMPUTE(K00,K01,K10,K11,V0,V1,V2) { \
  f32x4 s0a = {-8.f,-8.f,-8.f,-8.f}; f32x4 s1a = s0a, s0b = s0a, s1b = s0a; \
  s0a = __builtin_amdgcn_mfma_f32_16x16x32_bf16(qf0a, K00, s0a, 0,0,0); \
  s1a = __builtin_amdgcn_mfma_f32_16x16x32_bf16(qf0a, K10, s1a, 0,0,0); \
  s0b = __builtin_amdgcn_mfma_f32_16x16x32_bf16(qf0b, K00, s0b, 0,0,0); \
  s1b = __builtin_amdgcn_mfma_f32_16x16x32_bf16(qf0b, K10, s1b, 0,0,0); \
  s0a = __builtin_amdgcn_mfma_f32_16x16x32_bf16(qf1a, K01, s0a, 0,0,0); \
  s1a = __builtin_amdgcn_mfma_f32_16x16x32_bf16(qf1a, K11, s1a, 0,0,0); \
  s0b = __builtin_amdgcn_mfma_f32_16x16x32_bf16(qf1b, K01, s0b, 0,0,0); \
  s1b = __builtin_amdgcn_mfma_f32_16x16x32_bf16(qf1b, K11, s1b, 0,0,0); \
  f32x4 p0a, p1a, p0b, p1b; \
  _Pragma("unroll") \
  for (int r = 0; r < 4; ++r) { \
    p0a[r] = exp2f(s0a[r]); p1a[r] = exp2f(s1a[r]); \
    p0b[r] = exp2f(s0b[r]); p1b[r] = exp2f(s1b[r]); \
  } \
  la0a += p0a; la1a += p1a; la0b += p0b; la1b += p1b; \
  _Pragma("unroll") \
  for (int r = 0; r < 4; ++r) { \
    int row = quad*4 + r; \
    Psw[row*PS_STRIDE + n16]           = (ushort_t)(__float_as_uint(p0a[r]) >> 16); \
    Psw[row*PS_STRIDE + 16 + n16]      = (ushort_t)(__float_as_uint(p1a[r]) >> 16); \
    Psw[(16+row)*PS_STRIDE + n16]      = (ushort_t)(__float_as_uint(p0b[r]) >> 16); \
    Psw[(16+row)*PS_STRIDE + 16 + n16] = (ushort_t)(__float_as_uint(p1b[r]) >> 16); \
  } \
  bf16x8 paa = *(const bf16x8*)(Psw + n16*PS_STRIDE + quad*8); \
  bf16x8 pab = *(const bf16x8*)(Psw + (16+n16)*PS_STRIDE + quad*8); \
  o0a = __builtin_amdgcn_mfma_f32_16x16x32_bf16(paa, V0, o0a, 0,0,0); \
  o0b = __builtin_amdgcn_mfma_f32_16x16x32_bf16(pab, V0, o0b, 0,0,0); \
  o1a = __builtin_amdgcn_mfma_f32_16x16x32_bf16(paa, V1, o1a, 0,0,0); \
  o1b = __builtin_amdgcn_mfma_f32_16x16x32_bf16(pab, V1, o1b, 0,0,0); \
  o2a = __builtin_amdgcn_mfma_f32_16x16x32_bf16(paa, V2, o2a, 0,0,0); \
  o2b = __builtin_amdgcn_mfma_f32_16x16x32_bf16(pab, V2, o2b, 0,0,0); }

  bf16x8 ka0,ka1,ka2,ka3,va0,va1,va2;
  bf16x8 kb0,kb1,kb2,kb3,vb0,vb1,vb2;
  LOAD_TILE(0, ka0,ka1,ka2,ka3,va0,va1,va2);
  for (int t0 = 0; t0 < KCHUNK; t0 += 2*KT) {
    LOAD_TILE(t0 + KT, kb0,kb1,kb2,kb3,vb0,vb1,vb2);
    COMPUTE(ka0,ka1,ka2,ka3,va0,va1,va2);
    if (t0 + 2*KT < KCHUNK) {
      LOAD_TILE(t0 + 2*KT, ka0,ka1,ka2,ka3,va0,va1,va2);
    }
    COMPUTE(kb0,kb1,kb2,kb3,vb0,vb1,vb2);
  }
#undef LOAD_TILE
#undef COMPUTE

  float lra[4], lrb[4];
#pragma unroll
  for (int r = 0; r < 4; ++r) { lra[r] = la0a[r] + la1a[r]; lrb[r] = la0b[r] + la1b[r]; }
#pragma unroll
  for (int off = 1; off < 16; off <<= 1)
#pragma unroll
    for (int r = 0; r < 4; ++r) {
      lra[r] += __shfl_xor(lra[r], off, 64);
      lrb[r] += __shfl_xor(lrb[r], off, 64);
    }

  int gqa = bh*LQ + qt*128 + w*32 + quad*4;
  size_t base = (size_t)ks*NQROWS;
#pragma unroll
  for (int r = 0; r < 4; ++r) {
    size_t gq = base + gqa + r;
    ushort_t* pw = Pacc + gq*40;
    pw[n16]      = f2bf(o0a[r]);
    pw[16 + n16] = f2bf(o1a[r]);
    if (n16 < 8) pw[32 + n16] = f2bf(o2a[r]);
    if (n16 == 0) Pl[gq] = lra[r];
    size_t gq2 = gq + 16;
    ushort_t* pw2 = Pacc + gq2*40;
    pw2[n16]      = f2bf(o0b[r]);
    pw2[16 + n16] = f2bf(o1b[r]);
    if (n16 < 8) pw2[32 + n16] = f2bf(o2b[r]);
    if (n16 == 0) Pl[gq2] = lrb[r];
  }
}

// Merge KSPLIT bf16 partials per q-row -> bf16 O [4096][320]
__global__ __launch_bounds__(256) void attn_merge(
    const float* __restrict__ Pl, const ushort_t* __restrict__ Pacc,
    ushort_t* __restrict__ O)
{
  int idx = blockIdx.x*256 + threadIdx.x;   // 0..32767
  int bh = idx >> 11, qi = idx & (LQ-1);
  int b = bh >> 3, h = bh & 7;
  float L = 0.f;
#pragma unroll
  for (int k = 0; k < KSPLIT; ++k) L += Pl[(size_t)k*NQROWS + idx];
  float inv = 1.0f / L;
  ushort_t* orow = O + (size_t)(b*LQ + qi)*DIM + h*HD;
#pragma unroll
  for (int u = 0; u < 5; ++u) {           // 5 chunks of 8 cols
    float acc[8] = {0,0,0,0,0,0,0,0};
#pragma unroll
    for (int k = 0; k < KSPLIT; ++k) {
      const ushort_t* pr = Pacc + ((size_t)k*NQROWS + idx)*40 + u*8;
      ushort_t vbuf[8];
      *(uint4*)vbuf = *(const uint4*)pr;
#pragma unroll
      for (int j = 0; j < 8; ++j) acc[j] += bf2f(vbuf[j]);
    }
    ushort_t ob[8];
#pragma unroll
    for (int j = 0; j < 8; ++j) ob[j] = f2bf(acc[j]*inv);
    *(uint4*)(orow + u*8) = *(uint4*)ob;
  }
}

extern "C" void kernel_launch(void* const* d_in, const int* in_sizes, int n_in,
                              void* d_out, int out_size, void* d_ws, size_t ws_size,
                              hipStream_t stream) {
  const float* hidden = (const float*)d_in[0];
  // d_in[1] encoder_hidden_states: UNUSED (softmax rows sum to 1 -> cross == vH)
  const float* ln1_g = (const float*)d_in[2];
  const float* ln1_b = (const float*)d_in[3];
  const float* wq1   = (const float*)d_in[4];
  const float* wk1   = (const float*)d_in[5];
  const float* wv1   = (const float*)d_in[6];
  const float* wo1   = (const float*)d_in[7];
  const float* bo1   = (const float*)d_in[8];
  const float* ln2_g = (const float*)d_in[9];
  const float* ln2_b = (const float*)d_in[10];
  // d_in[11] wq2, d_in[12] wk2: UNUSED
  const float* wvh   = (const float*)d_in[13];
  const float* wo2   = (const float*)d_in[14];
  const float* bo2   = (const float*)d_in[15];
  const float* ln3_g = (const float*)d_in[16];
  const float* ln3_b = (const float*)d_in[17];
  const float* wff1  = (const float*)d_in[18];
  const float* bff1  = (const float*)d_in[19];
  const float* wff2  = (const float*)d_in[20];
  const float* bff2  = (const float*)d_in[21];
  float* out = (float*)d_out;

  // workspace: bf16 region (shorts) then fp32 region
  ushort_t* wsu = (ushort_t*)d_ws;
  ushort_t* wbf   = wsu;                          // WBF_TOTAL shorts
  ushort_t* lnb   = wbf + WBF_TOTAL;              // 4096*320
  ushort_t* qkvb  = lnb + (size_t)MROWS*DIM;      // 4096*960
  ushort_t* attnb = qkvb + (size_t)MROWS*3*DIM;   // 4096*320
  ushort_t* gegb  = attnb + (size_t)MROWS*DIM;    // 4096*1280
  ushort_t* wct   = gegb + (size_t)MROWS*FFD;     // 320*320
  ushort_t* vtb   = wct + 320*320;                // 16*48*2048
  ushort_t* kpb   = vtb + (size_t)16*48*2048;     // 16*2048*64
  ushort_t* Pacc  = kpb + (size_t)16*2048*64;     // KSPLIT*32768*40 bf16
  float* fws = (float*)(Pacc + (size_t)KSPLIT*NQROWS*40 + 64);
  float* h1   = fws;                              // 4096*320
  float* h2   = h1 + (size_t)MROWS*DIM;
  float* Pl   = h2 + (size_t)MROWS*DIM;           // KSPLIT*32768

  dim3 t256(256);
  dim3 gconv(800, 8);
  dim3 gqkv(15, 32);     // N=960, 128-row tiles -> 480 blocks
  dim3 g320(5, 64);      // N=320, 64-row tiles -> 320 blocks
  dim3 gwc(5, 5);        // 320x320
  dim3 gffg(20, 32);     // ff1+geglu, 128-row tiles -> 640 blocks
  dim3 gvt(32, 16);
  dim3 gattn(16*16*KSPLIT);   // flat 1024 4-wave blocks, XCD swizzle inside

  convw_kernel<<<gconv, t256, 0, stream>>>(wq1, wk1, wv1, wo1, wo2, wff1, wff2, wvh, wbf);
  // Wc^T = wo2^T @ wvh^T (tiny)
  mgemm<<<gwc, t256, 0, stream>>>(wbf + OFF_WO2T, DIM, wbf + OFF_WVHB, DIM,
                                  nullptr, nullptr, nullptr, wct, DIM, DIM);

  // Stage 1: self-attention
  ln_kernel<<<MROWS/4, t256, 0, stream>>>(hidden, ln1_g, ln1_b, lnb);
  mgemm128<<<gqkv, t256, 0, stream>>>(lnb, DIM, wbf + OFF_WQKVT, DIM,
                                      qkvb, 3*DIM, DIM);
  vt_kernel<<<gvt, t256, 0, stream>>>(qkvb, vtb, kpb);
  attn_mfma<<<gattn, t256, 0, stream>>>(qkvb, kpb, vtb, Pl, Pacc);
  attn_merge<<<NQROWS/256, t256, 0, stream>>>(Pl, Pacc, attnb);
  mgemm<<<g320, t256, 0, stream>>>(attnb, DIM, wbf + OFF_WO1T, DIM, bo1, hidden,
                                   h1, nullptr, DIM, DIM);

  // Stage 2: cross == ln2(h1) @ (wvh@wo2) + bo2 + h1   (softmax sums to 1)
  ln_kernel<<<MROWS/4, t256, 0, stream>>>(h1, ln2_g, ln2_b, lnb);
  mgemm<<<g320, t256, 0, stream>>>(lnb, DIM, wct, DIM, bo2, h1,
                                   h2, nullptr, DIM, DIM);

  // Stage 3: GEGLU FF
  ln_kernel<<<MROWS/4, t256, 0, stream>>>(h2, ln3_g, ln3_b, lnb);
  ff1_geglu<<<gffg, t256, 0, stream>>>(lnb, wbf + OFF_WFF1T, bff1, gegb);
  mgemm<<<g320, t256, 0, stream>>>(gegb, FFD, wbf + OFF_WFF2T, FFD, bff2, h2,
                                   out, nullptr, DIM, FFD);
}